// Round 6
// baseline (1036.601 us; speedup 1.0000x reference)
//
#include <hip/hip_runtime.h>
#include <math.h>

#define N_NODES 100000
#define F_IN    100
#define HIDDEN  16
#define N_CLASS 18

#define BKT_SHIFT 7
#define BKT_NODES 128                                   // nodes per bucket
#define NBKT ((N_NODES + BKT_NODES - 1) / BKT_NODES)    // 782
#define TILE 8192                                       // edges per k_bucket block
#define AGG_PAD 17                                      // padded LDS row stride (banks)

typedef float f4 __attribute__((ext_vector_type(4)));

#define ASM_LOAD_B32(dst, ptr) \
    asm volatile("global_load_dword %0, %1, off" : "=v"(dst) : "v"(ptr))
#define ASM_LOAD_B128(dst, ptr) \
    asm volatile("global_load_dwordx4 %0, %1, off" : "=v"(dst) : "v"(ptr))

// ---- edge dtype detector: int64 little-endian (values < 2^31) has all-zero odd int32 words
__global__ void k_detect(const int* __restrict__ ei, int* __restrict__ flag) {
    int z = 1;
    for (int i = 0; i < 16; ++i) {
        if (ei[2 * i + 1] != 0) z = 0;
    }
    *flag = z;  // 1 => int64 layout, 0 => int32 layout
}

__device__ __forceinline__ int edge_at(const int* __restrict__ ei, long long idx, int is64) {
    return is64 ? ei[2 * idx] : ei[idx];
}

// ---- per-node in-degree histogram (for dinv and bucket counts)
__global__ __launch_bounds__(256) void k_hist(const int* __restrict__ ei, long long E,
                                              const int* __restrict__ flag,
                                              int* __restrict__ cnt) {
    long long e = (long long)blockIdx.x * 256 + threadIdx.x;
    if (e >= E) return;
    int is64 = *flag;
    int d = edge_at(ei, E + e, is64);
    atomicAdd(&cnt[d], 1);
}

__global__ __launch_bounds__(256) void k_dinv(const int* __restrict__ cnt,
                                              float* __restrict__ dinv) {
    int i = blockIdx.x * 256 + threadIdx.x;
    if (i < N_NODES) dinv[i] = rsqrtf((float)cnt[i] + 1.0f);
}

// ---- bucket totals from per-node counts
__global__ __launch_bounds__(256) void k_bktcnt(const int* __restrict__ cnt,
                                                int* __restrict__ bcnt) {
    int b = blockIdx.x * 256 + threadIdx.x;
    if (b >= NBKT) return;
    int n0 = b * BKT_NODES;
    int n1 = min(n0 + BKT_NODES, N_NODES);
    int s = 0;
    for (int n = n0; n < n1; ++n) s += cnt[n];
    bcnt[b] = s;
}

// ---- single-block scan over 782 bucket counts -> bases + global cursors
__global__ __launch_bounds__(1024) void k_bktscan(const int* __restrict__ bcnt,
                                                  int* __restrict__ gcur,
                                                  int* __restrict__ bkt_base) {
    __shared__ int s[1024];
    int tid = threadIdx.x;
    int v = (tid < NBKT) ? bcnt[tid] : 0;
    s[tid] = v;
    __syncthreads();
    for (int off = 1; off < 1024; off <<= 1) {
        int t = (tid >= off) ? s[tid - off] : 0;
        __syncthreads();
        s[tid] += t;
        __syncthreads();
    }
    if (tid < NBKT) {
        int e = s[tid] - v;  // exclusive
        gcur[tid] = e;
        bkt_base[tid] = e;
    }
    if (tid == 1023) bkt_base[NBKT] = s[1023];
}

// ---- level-1 split: per-tile LDS counting sort by bucket, coalesced packed writes
// pairs[pos] = src | (dst&127)<<17   (src < 2^17, dst-local 7 bits)
__global__ __launch_bounds__(256) void k_bucket(const int* __restrict__ ei, long long E,
                                                const int* __restrict__ flag,
                                                int* __restrict__ gcur,
                                                int* __restrict__ pairs) {
    __shared__ int hist[NBKT];
    __shared__ int lbase[NBKT];
    __shared__ int gbase[NBKT];
    __shared__ int lcur[NBKT];
    __shared__ unsigned short perm[TILE];
    __shared__ int ts[256];
    int tid = threadIdx.x;
    int is64 = *flag;
    long long e0 = (long long)blockIdx.x * TILE;
    int n = (int)(((E - e0) < (long long)TILE) ? (E - e0) : (long long)TILE);

    for (int i = tid; i < NBKT; i += 256) hist[i] = 0;
    __syncthreads();
    for (int i = tid; i < n; i += 256) {
        int d = edge_at(ei, E + e0 + i, is64);
        atomicAdd(&hist[d >> BKT_SHIFT], 1);
    }
    __syncthreads();

    // exclusive scan of hist into lbase; thread owns 4 consecutive buckets
    int b0 = tid * 4;
    int h0 = (b0 + 0 < NBKT) ? hist[b0 + 0] : 0;
    int h1 = (b0 + 1 < NBKT) ? hist[b0 + 1] : 0;
    int h2 = (b0 + 2 < NBKT) ? hist[b0 + 2] : 0;
    int h3 = (b0 + 3 < NBKT) ? hist[b0 + 3] : 0;
    int tsum = h0 + h1 + h2 + h3;
    ts[tid] = tsum;
    __syncthreads();
    for (int off = 1; off < 256; off <<= 1) {
        int t = (tid >= off) ? ts[tid - off] : 0;
        __syncthreads();
        ts[tid] += t;
        __syncthreads();
    }
    int eb = ts[tid] - tsum;
    if (b0 + 0 < NBKT) lbase[b0 + 0] = eb;
    if (b0 + 1 < NBKT) lbase[b0 + 1] = eb + h0;
    if (b0 + 2 < NBKT) lbase[b0 + 2] = eb + h0 + h1;
    if (b0 + 3 < NBKT) lbase[b0 + 3] = eb + h0 + h1 + h2;

    // reserve this block's run in each bucket's global region
    for (int b = tid; b < NBKT; b += 256) {
        int c = hist[b];
        gbase[b] = (c > 0) ? atomicAdd(&gcur[b], c) : 0;
    }
    __syncthreads();
    for (int i = tid; i < NBKT; i += 256) lcur[i] = lbase[i];
    __syncthreads();

    // local binning (perm holds tile-local edge ids, grouped by bucket)
    for (int i = tid; i < n; i += 256) {
        int d = edge_at(ei, E + e0 + i, is64);
        int l = atomicAdd(&lcur[d >> BKT_SHIFT], 1);
        perm[l] = (unsigned short)i;
    }
    __syncthreads();

    // write out: consecutive k within a bucket-run -> consecutive positions
    for (int k = tid; k < n; k += 256) {
        int i = perm[k];
        int s = edge_at(ei, e0 + i, is64);
        int d = edge_at(ei, E + e0 + i, is64);
        int b = d >> BKT_SHIFT;
        int pos = gbase[b] + (k - lbase[b]);
        pairs[pos] = s | ((d & (BKT_NODES - 1)) << 17);
    }
}

// ---- h = relu(x @ W1 + b1)   [N,100]@[100,16]
__global__ __launch_bounds__(256) void k_lin1(const float* __restrict__ x,
                                              const float* __restrict__ W1,
                                              const float* __restrict__ b1,
                                              float* __restrict__ h) {
    __shared__ float sW[F_IN * HIDDEN];
    __shared__ float sb[HIDDEN];
    for (int i = threadIdx.x; i < F_IN * HIDDEN; i += 256) sW[i] = W1[i];
    if (threadIdx.x < HIDDEN) sb[threadIdx.x] = b1[threadIdx.x];
    __syncthreads();
    int node = blockIdx.x * 256 + threadIdx.x;
    if (node >= N_NODES) return;

    float acc[HIDDEN];
#pragma unroll
    for (int j = 0; j < HIDDEN; ++j) acc[j] = sb[j];

    const float4* x4 = reinterpret_cast<const float4*>(x + (long long)node * F_IN);
#pragma unroll 2
    for (int k4 = 0; k4 < F_IN / 4; ++k4) {
        float4 xv = x4[k4];
        const float* w = &sW[k4 * 4 * HIDDEN];
#pragma unroll
        for (int j = 0; j < HIDDEN; ++j) {
            acc[j] += xv.x * w[0 * HIDDEN + j];
            acc[j] += xv.y * w[1 * HIDDEN + j];
            acc[j] += xv.z * w[2 * HIDDEN + j];
            acc[j] += xv.w * w[3 * HIDDEN + j];
        }
    }
    float4* hr = reinterpret_cast<float4*>(h + (long long)node * HIDDEN);
#pragma unroll
    for (int q = 0; q < HIDDEN / 4; ++q) {
        float4 o;
        o.x = fmaxf(acc[q * 4 + 0], 0.0f);
        o.y = fmaxf(acc[q * 4 + 1], 0.0f);
        o.z = fmaxf(acc[q * 4 + 2], 0.0f);
        o.w = fmaxf(acc[q * 4 + 3], 0.0f);
        hr[q] = o;
    }
}

// ---- tmp' = dinv[i] * (h @ W)
__global__ __launch_bounds__(256) void k_mm16(const float* __restrict__ h,
                                              const float* __restrict__ W,
                                              const float* __restrict__ dinv,
                                              float* __restrict__ tmpp) {
    __shared__ float sW[HIDDEN * HIDDEN];
    if (threadIdx.x < HIDDEN * HIDDEN) sW[threadIdx.x] = W[threadIdx.x];
    __syncthreads();
    int node = blockIdx.x * 256 + threadIdx.x;
    if (node >= N_NODES) return;

    float hv[HIDDEN];
    const float4* hr = reinterpret_cast<const float4*>(h + (long long)node * HIDDEN);
#pragma unroll
    for (int q = 0; q < HIDDEN / 4; ++q) {
        float4 v = hr[q];
        hv[q * 4 + 0] = v.x; hv[q * 4 + 1] = v.y;
        hv[q * 4 + 2] = v.z; hv[q * 4 + 3] = v.w;
    }
    float di = dinv[node];
    float out[HIDDEN];
#pragma unroll
    for (int j = 0; j < HIDDEN; ++j) out[j] = 0.0f;
#pragma unroll
    for (int k = 0; k < HIDDEN; ++k) {
        float hk = hv[k];
#pragma unroll
        for (int j = 0; j < HIDDEN; ++j) out[j] += hk * sW[k * HIDDEN + j];
    }
    float4* tp = reinterpret_cast<float4*>(tmpp + (long long)node * HIDDEN);
#pragma unroll
    for (int q = 0; q < HIDDEN / 4; ++q) {
        float4 o;
        o.x = di * out[q * 4 + 0];
        o.y = di * out[q * 4 + 1];
        o.z = di * out[q * 4 + 2];
        o.w = di * out[q * 4 + 3];
        tp[q] = o;
    }
}

// ---- per-bucket aggregation in LDS; asm-forced 8-deep MLP; fused epilogue
// h[n] = relu(dinv[n]*(sum_src tmpp[src] + tmpp[n]) + b)
__global__ __launch_bounds__(512) void k_aggr(const int* __restrict__ bkt_base,
                                              const int* __restrict__ pairs,
                                              const float* __restrict__ tmpp,
                                              const float* __restrict__ dinv,
                                              const float* __restrict__ b,
                                              float* __restrict__ h) {
    __shared__ float agg[BKT_NODES * AGG_PAD];  // 128*17*4 = 8704 B
    int tid = threadIdx.x;
    int bk = blockIdx.x;
    for (int i = tid; i < BKT_NODES * AGG_PAD; i += 512) agg[i] = 0.0f;
    __syncthreads();
    int i0 = bkt_base[bk], i1 = bkt_base[bk + 1];
    int cnt = i1 - i0;
    int qq = tid & 3;           // quarter index (float4 within the 16-float row)
    int q4 = qq * 4;
    int eo = tid >> 2;          // 0..127 edge slot
    const f4* t4 = reinterpret_cast<const f4*>(tmpp);

    int niter = (cnt + 1023) >> 10;   // 8 slabs of 128 edges per iteration
    int base = i0 + eo;
    for (int it = 0; it < niter; ++it, base += 1024) {
        int v0, v1, v2, v3, v4, v5, v6, v7;
        float m0, m1, m2, m3, m4, m5, m6, m7;
        const int *p0, *p1, *p2, *p3, *p4, *p5, *p6, *p7;
#define PREP(K, PK, MK)                                        \
        {   int ik = base + (K) * 128;                         \
            MK = (ik < i1) ? 1.0f : 0.0f;                      \
            PK = pairs + ((ik < i1) ? ik : i0); }
        PREP(0, p0, m0) PREP(1, p1, m1) PREP(2, p2, m2) PREP(3, p3, m3)
        PREP(4, p4, m4) PREP(5, p5, m5) PREP(6, p6, m6) PREP(7, p7, m7)
#undef PREP
        // phase A: 8 independent pairs-word loads, all in flight
        ASM_LOAD_B32(v0, p0); ASM_LOAD_B32(v1, p1);
        ASM_LOAD_B32(v2, p2); ASM_LOAD_B32(v3, p3);
        ASM_LOAD_B32(v4, p4); ASM_LOAD_B32(v5, p5);
        ASM_LOAD_B32(v6, p6); ASM_LOAD_B32(v7, p7);
        asm volatile("s_waitcnt vmcnt(0)"
                     : "+v"(v0), "+v"(v1), "+v"(v2), "+v"(v3),
                       "+v"(v4), "+v"(v5), "+v"(v6), "+v"(v7));
        // phase B: 8 independent float4 gathers (16 distinct lines per wave instr)
        const f4 *g0 = t4 + ((v0 & 0x1FFFF) * 4 + qq);
        const f4 *g1 = t4 + ((v1 & 0x1FFFF) * 4 + qq);
        const f4 *g2 = t4 + ((v2 & 0x1FFFF) * 4 + qq);
        const f4 *g3 = t4 + ((v3 & 0x1FFFF) * 4 + qq);
        const f4 *g4 = t4 + ((v4 & 0x1FFFF) * 4 + qq);
        const f4 *g5 = t4 + ((v5 & 0x1FFFF) * 4 + qq);
        const f4 *g6 = t4 + ((v6 & 0x1FFFF) * 4 + qq);
        const f4 *g7 = t4 + ((v7 & 0x1FFFF) * 4 + qq);
        f4 a0, a1, a2, a3, a4, a5, a6, a7;
        ASM_LOAD_B128(a0, g0); ASM_LOAD_B128(a1, g1);
        ASM_LOAD_B128(a2, g2); ASM_LOAD_B128(a3, g3);
        ASM_LOAD_B128(a4, g4); ASM_LOAD_B128(a5, g5);
        ASM_LOAD_B128(a6, g6); ASM_LOAD_B128(a7, g7);
        asm volatile("s_waitcnt vmcnt(0)"
                     : "+v"(a0), "+v"(a1), "+v"(a2), "+v"(a3),
                       "+v"(a4), "+v"(a5), "+v"(a6), "+v"(a7));
        // phase C: LDS accumulation (padded rows -> ~conflict-free; masked lanes add 0)
#define ACCUM(VK, AK, MK)                                      \
        {   int d = ((VK) >> 17) * AGG_PAD + q4;               \
            atomicAdd(&agg[d + 0], AK.x * MK);                 \
            atomicAdd(&agg[d + 1], AK.y * MK);                 \
            atomicAdd(&agg[d + 2], AK.z * MK);                 \
            atomicAdd(&agg[d + 3], AK.w * MK); }
        ACCUM(v0, a0, m0) ACCUM(v1, a1, m1) ACCUM(v2, a2, m2) ACCUM(v3, a3, m3)
        ACCUM(v4, a4, m4) ACCUM(v5, a5, m5) ACCUM(v6, a6, m6) ACCUM(v7, a7, m7)
#undef ACCUM
    }
    __syncthreads();
    int nb = bk * BKT_NODES;
    for (int i = tid; i < BKT_NODES * HIDDEN; i += 512) {
        int dl = i >> 4, ff = i & 15;
        int node = nb + dl;
        if (node < N_NODES) {
            float val = dinv[node] * (agg[dl * AGG_PAD + ff] + tmpp[(long long)node * HIDDEN + ff]) + b[ff];
            h[(long long)node * HIDDEN + ff] = fmaxf(val, 0.0f);
        }
    }
}

// ---- out = log_softmax(h @ W2 + b2)
__global__ __launch_bounds__(256) void k_out(const float* __restrict__ h,
                                             const float* __restrict__ W2,
                                             const float* __restrict__ b2,
                                             float* __restrict__ out) {
    __shared__ float sW[HIDDEN * N_CLASS];
    __shared__ float sb[N_CLASS];
    for (int i = threadIdx.x; i < HIDDEN * N_CLASS; i += 256) sW[i] = W2[i];
    if (threadIdx.x < N_CLASS) sb[threadIdx.x] = b2[threadIdx.x];
    __syncthreads();
    int node = blockIdx.x * 256 + threadIdx.x;
    if (node >= N_NODES) return;

    float hv[HIDDEN];
    const float4* hr = reinterpret_cast<const float4*>(h + (long long)node * HIDDEN);
#pragma unroll
    for (int q = 0; q < HIDDEN / 4; ++q) {
        float4 v = hr[q];
        hv[q * 4 + 0] = v.x; hv[q * 4 + 1] = v.y;
        hv[q * 4 + 2] = v.z; hv[q * 4 + 3] = v.w;
    }
    float z[N_CLASS];
#pragma unroll
    for (int c = 0; c < N_CLASS; ++c) z[c] = sb[c];
#pragma unroll
    for (int k = 0; k < HIDDEN; ++k) {
        float hk = hv[k];
#pragma unroll
        for (int c = 0; c < N_CLASS; ++c) z[c] += hk * sW[k * N_CLASS + c];
    }
    float m = z[0];
#pragma unroll
    for (int c = 1; c < N_CLASS; ++c) m = fmaxf(m, z[c]);
    float ssum = 0.0f;
#pragma unroll
    for (int c = 0; c < N_CLASS; ++c) ssum += expf(z[c] - m);
    float l = m + logf(ssum);
    float* orow = out + (long long)node * N_CLASS;
#pragma unroll
    for (int c = 0; c < N_CLASS; ++c) orow[c] = z[c] - l;
}

static inline char* align256(char* p) {
    return (char*)(((size_t)p + 255) & ~(size_t)255);
}

extern "C" void kernel_launch(void* const* d_in, const int* in_sizes, int n_in,
                              void* d_out, int out_size, void* d_ws, size_t ws_size,
                              hipStream_t stream) {
    const float* x   = (const float*)d_in[0];
    const int*   ei  = (const int*)d_in[1];
    const float* W1  = (const float*)d_in[2];
    const float* b1  = (const float*)d_in[3];
    const float* Wc0 = (const float*)d_in[4];
    const float* bc0 = (const float*)d_in[5];
    const float* Wc1 = (const float*)d_in[6];
    const float* bc1 = (const float*)d_in[7];
    const float* W2  = (const float*)d_in[8];
    const float* b2  = (const float*)d_in[9];
    float* out = (float*)d_out;

    long long E = (long long)in_sizes[1] / 2;

    char* p = (char*)d_ws;
    int* flag      = (int*)p;            p = align256(p + sizeof(int));
    int* cnt       = (int*)p;            p = align256(p + sizeof(int) * N_NODES);
    float* dinv    = (float*)p;          p = align256(p + sizeof(float) * N_NODES);
    int* bcnt      = (int*)p;            p = align256(p + sizeof(int) * NBKT);
    int* bkt_base  = (int*)p;            p = align256(p + sizeof(int) * (NBKT + 1));
    int* gcur      = (int*)p;            p = align256(p + sizeof(int) * NBKT);
    int* pairs     = (int*)p;            p = align256(p + sizeof(int) * E);
    float* h       = (float*)p;          p = align256(p + sizeof(float) * (size_t)N_NODES * HIDDEN);
    float* tmpp    = (float*)p;          p = align256(p + sizeof(float) * (size_t)N_NODES * HIDDEN);

    const int nblk_node   = (N_NODES + 255) / 256;
    const int nblk_edge   = (int)((E + 255) / 256);
    const int nblk_bucket = (int)((E + TILE - 1) / TILE);
    const int nblk_bcnt   = (NBKT + 255) / 256;

    hipMemsetAsync(cnt, 0, sizeof(int) * N_NODES, stream);
    k_detect<<<1, 1, 0, stream>>>(ei, flag);
    k_hist<<<nblk_edge, 256, 0, stream>>>(ei, E, flag, cnt);
    k_dinv<<<nblk_node, 256, 0, stream>>>(cnt, dinv);

    k_bktcnt<<<nblk_bcnt, 256, 0, stream>>>(cnt, bcnt);
    k_bktscan<<<1, 1024, 0, stream>>>(bcnt, gcur, bkt_base);
    k_bucket<<<nblk_bucket, 256, 0, stream>>>(ei, E, flag, gcur, pairs);

    k_lin1<<<nblk_node, 256, 0, stream>>>(x, W1, b1, h);

    // conv 1
    k_mm16<<<nblk_node, 256, 0, stream>>>(h, Wc0, dinv, tmpp);
    k_aggr<<<NBKT, 512, 0, stream>>>(bkt_base, pairs, tmpp, dinv, bc0, h);

    // conv 2
    k_mm16<<<nblk_node, 256, 0, stream>>>(h, Wc1, dinv, tmpp);
    k_aggr<<<NBKT, 512, 0, stream>>>(bkt_base, pairs, tmpp, dinv, bc1, h);

    k_out<<<nblk_node, 256, 0, stream>>>(h, W2, b2, out);
}

// Round 7
// 912.701 us; speedup vs baseline: 1.1358x; 1.1358x over previous
//
#include <hip/hip_runtime.h>
#include <hip/hip_fp16.h>
#include <math.h>

#define N_NODES 100000
#define F_IN    100
#define HIDDEN  16
#define N_CLASS 18

#define BKT_SHIFT 7
#define BKT_NODES 128                                   // nodes per bucket
#define NBKT ((N_NODES + BKT_NODES - 1) / BKT_NODES)    // 782
#define TILE 8192                                       // edges per k_bucket block
#define AGG_PAD 17                                      // padded LDS row stride (banks)

// ---- edge dtype detector: int64 little-endian (values < 2^31) has all-zero odd int32 words
__global__ void k_detect(const int* __restrict__ ei, int* __restrict__ flag) {
    int z = 1;
    for (int i = 0; i < 16; ++i) {
        if (ei[2 * i + 1] != 0) z = 0;
    }
    *flag = z;  // 1 => int64 layout, 0 => int32 layout
}

__device__ __forceinline__ int edge_at(const int* __restrict__ ei, long long idx, int is64) {
    return is64 ? ei[2 * idx] : ei[idx];
}

// ---- per-node in-degree histogram (for dinv and bucket counts)
__global__ __launch_bounds__(256) void k_hist(const int* __restrict__ ei, long long E,
                                              const int* __restrict__ flag,
                                              int* __restrict__ cnt) {
    long long e = (long long)blockIdx.x * 256 + threadIdx.x;
    if (e >= E) return;
    int is64 = *flag;
    int d = edge_at(ei, E + e, is64);
    atomicAdd(&cnt[d], 1);
}

__global__ __launch_bounds__(256) void k_dinv(const int* __restrict__ cnt,
                                              float* __restrict__ dinv) {
    int i = blockIdx.x * 256 + threadIdx.x;
    if (i < N_NODES) dinv[i] = rsqrtf((float)cnt[i] + 1.0f);
}

// ---- bucket totals from per-node counts
__global__ __launch_bounds__(256) void k_bktcnt(const int* __restrict__ cnt,
                                                int* __restrict__ bcnt) {
    int b = blockIdx.x * 256 + threadIdx.x;
    if (b >= NBKT) return;
    int n0 = b * BKT_NODES;
    int n1 = min(n0 + BKT_NODES, N_NODES);
    int s = 0;
    for (int n = n0; n < n1; ++n) s += cnt[n];
    bcnt[b] = s;
}

// ---- single-block scan over 782 bucket counts -> bases + global cursors
__global__ __launch_bounds__(1024) void k_bktscan(const int* __restrict__ bcnt,
                                                  int* __restrict__ gcur,
                                                  int* __restrict__ bkt_base) {
    __shared__ int s[1024];
    int tid = threadIdx.x;
    int v = (tid < NBKT) ? bcnt[tid] : 0;
    s[tid] = v;
    __syncthreads();
    for (int off = 1; off < 1024; off <<= 1) {
        int t = (tid >= off) ? s[tid - off] : 0;
        __syncthreads();
        s[tid] += t;
        __syncthreads();
    }
    if (tid < NBKT) {
        int e = s[tid] - v;  // exclusive
        gcur[tid] = e;
        bkt_base[tid] = e;
    }
    if (tid == 1023) bkt_base[NBKT] = s[1023];
}

// ---- level-1 split: per-tile LDS counting sort by bucket, coalesced packed writes
// pairs[pos] = src | (dst&127)<<17   (src < 2^17, dst-local 7 bits)
__global__ __launch_bounds__(256) void k_bucket(const int* __restrict__ ei, long long E,
                                                const int* __restrict__ flag,
                                                int* __restrict__ gcur,
                                                int* __restrict__ pairs) {
    __shared__ int hist[NBKT];
    __shared__ int lbase[NBKT];
    __shared__ int gbase[NBKT];
    __shared__ int lcur[NBKT];
    __shared__ unsigned short perm[TILE];
    __shared__ int ts[256];
    int tid = threadIdx.x;
    int is64 = *flag;
    long long e0 = (long long)blockIdx.x * TILE;
    int n = (int)(((E - e0) < (long long)TILE) ? (E - e0) : (long long)TILE);

    for (int i = tid; i < NBKT; i += 256) hist[i] = 0;
    __syncthreads();
    for (int i = tid; i < n; i += 256) {
        int d = edge_at(ei, E + e0 + i, is64);
        atomicAdd(&hist[d >> BKT_SHIFT], 1);
    }
    __syncthreads();

    // exclusive scan of hist into lbase; thread owns 4 consecutive buckets
    int b0 = tid * 4;
    int h0 = (b0 + 0 < NBKT) ? hist[b0 + 0] : 0;
    int h1 = (b0 + 1 < NBKT) ? hist[b0 + 1] : 0;
    int h2 = (b0 + 2 < NBKT) ? hist[b0 + 2] : 0;
    int h3 = (b0 + 3 < NBKT) ? hist[b0 + 3] : 0;
    int tsum = h0 + h1 + h2 + h3;
    ts[tid] = tsum;
    __syncthreads();
    for (int off = 1; off < 256; off <<= 1) {
        int t = (tid >= off) ? ts[tid - off] : 0;
        __syncthreads();
        ts[tid] += t;
        __syncthreads();
    }
    int eb = ts[tid] - tsum;
    if (b0 + 0 < NBKT) lbase[b0 + 0] = eb;
    if (b0 + 1 < NBKT) lbase[b0 + 1] = eb + h0;
    if (b0 + 2 < NBKT) lbase[b0 + 2] = eb + h0 + h1;
    if (b0 + 3 < NBKT) lbase[b0 + 3] = eb + h0 + h1 + h2;

    // reserve this block's run in each bucket's global region
    for (int b = tid; b < NBKT; b += 256) {
        int c = hist[b];
        gbase[b] = (c > 0) ? atomicAdd(&gcur[b], c) : 0;
    }
    __syncthreads();
    for (int i = tid; i < NBKT; i += 256) lcur[i] = lbase[i];
    __syncthreads();

    // local binning (perm holds tile-local edge ids, grouped by bucket)
    for (int i = tid; i < n; i += 256) {
        int d = edge_at(ei, E + e0 + i, is64);
        int l = atomicAdd(&lcur[d >> BKT_SHIFT], 1);
        perm[l] = (unsigned short)i;
    }
    __syncthreads();

    // write out: consecutive k within a bucket-run -> consecutive positions
    for (int k = tid; k < n; k += 256) {
        int i = perm[k];
        int s = edge_at(ei, e0 + i, is64);
        int d = edge_at(ei, E + e0 + i, is64);
        int b = d >> BKT_SHIFT;
        int pos = gbase[b] + (k - lbase[b]);
        pairs[pos] = s | ((d & (BKT_NODES - 1)) << 17);
    }
}

// ---- h = relu(x @ W1 + b1)   [N,100]@[100,16]
__global__ __launch_bounds__(256) void k_lin1(const float* __restrict__ x,
                                              const float* __restrict__ W1,
                                              const float* __restrict__ b1,
                                              float* __restrict__ h) {
    __shared__ float sW[F_IN * HIDDEN];
    __shared__ float sb[HIDDEN];
    for (int i = threadIdx.x; i < F_IN * HIDDEN; i += 256) sW[i] = W1[i];
    if (threadIdx.x < HIDDEN) sb[threadIdx.x] = b1[threadIdx.x];
    __syncthreads();
    int node = blockIdx.x * 256 + threadIdx.x;
    if (node >= N_NODES) return;

    float acc[HIDDEN];
#pragma unroll
    for (int j = 0; j < HIDDEN; ++j) acc[j] = sb[j];

    const float4* x4 = reinterpret_cast<const float4*>(x + (long long)node * F_IN);
#pragma unroll 2
    for (int k4 = 0; k4 < F_IN / 4; ++k4) {
        float4 xv = x4[k4];
        const float* w = &sW[k4 * 4 * HIDDEN];
#pragma unroll
        for (int j = 0; j < HIDDEN; ++j) {
            acc[j] += xv.x * w[0 * HIDDEN + j];
            acc[j] += xv.y * w[1 * HIDDEN + j];
            acc[j] += xv.z * w[2 * HIDDEN + j];
            acc[j] += xv.w * w[3 * HIDDEN + j];
        }
    }
    float4* hr = reinterpret_cast<float4*>(h + (long long)node * HIDDEN);
#pragma unroll
    for (int q = 0; q < HIDDEN / 4; ++q) {
        float4 o;
        o.x = fmaxf(acc[q * 4 + 0], 0.0f);
        o.y = fmaxf(acc[q * 4 + 1], 0.0f);
        o.z = fmaxf(acc[q * 4 + 2], 0.0f);
        o.w = fmaxf(acc[q * 4 + 3], 0.0f);
        hr[q] = o;
    }
}

// ---- tmp' = fp16( dinv[i] * (h @ W) )   [table shrinks to 3.2 MB -> per-XCD L2 resident]
__global__ __launch_bounds__(256) void k_mm16(const float* __restrict__ h,
                                              const float* __restrict__ W,
                                              const float* __restrict__ dinv,
                                              __half* __restrict__ tmpp) {
    __shared__ float sW[HIDDEN * HIDDEN];
    if (threadIdx.x < HIDDEN * HIDDEN) sW[threadIdx.x] = W[threadIdx.x];
    __syncthreads();
    int node = blockIdx.x * 256 + threadIdx.x;
    if (node >= N_NODES) return;

    float hv[HIDDEN];
    const float4* hr = reinterpret_cast<const float4*>(h + (long long)node * HIDDEN);
#pragma unroll
    for (int q = 0; q < HIDDEN / 4; ++q) {
        float4 v = hr[q];
        hv[q * 4 + 0] = v.x; hv[q * 4 + 1] = v.y;
        hv[q * 4 + 2] = v.z; hv[q * 4 + 3] = v.w;
    }
    float di = dinv[node];
    float out[HIDDEN];
#pragma unroll
    for (int j = 0; j < HIDDEN; ++j) out[j] = 0.0f;
#pragma unroll
    for (int k = 0; k < HIDDEN; ++k) {
        float hk = hv[k];
#pragma unroll
        for (int j = 0; j < HIDDEN; ++j) out[j] += hk * sW[k * HIDDEN + j];
    }
    __half2 packed[8];
#pragma unroll
    for (int j = 0; j < 8; ++j)
        packed[j] = __floats2half2_rn(di * out[2 * j], di * out[2 * j + 1]);
    float4* tp = reinterpret_cast<float4*>(tmpp + (long long)node * HIDDEN);
    const float4* ps = reinterpret_cast<const float4*>(packed);
    tp[0] = ps[0];
    tp[1] = ps[1];
}

// ---- per-bucket aggregation in LDS; fp16 gathers (2 lanes/edge, 16 B each); fused epilogue
// h[n] = relu(dinv[n]*(sum_src tmpp[src] + tmpp[n]) + b)
__global__ __launch_bounds__(512) void k_aggr(const int* __restrict__ bkt_base,
                                              const int* __restrict__ pairs,
                                              const __half* __restrict__ tmpp,
                                              const float* __restrict__ dinv,
                                              const float* __restrict__ b,
                                              float* __restrict__ h) {
    __shared__ float agg[BKT_NODES * AGG_PAD];  // 128*17*4 = 8704 B
    int tid = threadIdx.x;
    int bk = blockIdx.x;
    for (int i = tid; i < BKT_NODES * AGG_PAD; i += 512) agg[i] = 0.0f;
    __syncthreads();
    int i0 = bkt_base[bk], i1 = bkt_base[bk + 1];
    int hp = tid & 1;            // which 16-B half of the 32-B row
    int eo = tid >> 1;           // 0..255 edge slot

    for (int e = i0 + eo; e < i1; e += 256) {
        int v = pairs[e];
        const float4* rp = reinterpret_cast<const float4*>(
                               tmpp + (long long)(v & 0x1FFFF) * HIDDEN) + hp;
        float4 rv = *rp;                       // 8 halves
        const __half2* h2 = reinterpret_cast<const __half2*>(&rv);
        int base = (v >> 17) * AGG_PAD + hp * 8;
#pragma unroll
        for (int j = 0; j < 4; ++j) {
            float2 f = __half22float2(h2[j]);
            atomicAdd(&agg[base + 2 * j + 0], f.x);
            atomicAdd(&agg[base + 2 * j + 1], f.y);
        }
    }
    __syncthreads();
    int nb = bk * BKT_NODES;
    for (int i = tid; i < BKT_NODES * HIDDEN; i += 512) {
        int dl = i >> 4, ff = i & 15;
        int node = nb + dl;
        if (node < N_NODES) {
            float self = __half2float(tmpp[(long long)node * HIDDEN + ff]);
            float val = dinv[node] * (agg[dl * AGG_PAD + ff] + self) + b[ff];
            h[(long long)node * HIDDEN + ff] = fmaxf(val, 0.0f);
        }
    }
}

// ---- out = log_softmax(h @ W2 + b2)
__global__ __launch_bounds__(256) void k_out(const float* __restrict__ h,
                                             const float* __restrict__ W2,
                                             const float* __restrict__ b2,
                                             float* __restrict__ out) {
    __shared__ float sW[HIDDEN * N_CLASS];
    __shared__ float sb[N_CLASS];
    for (int i = threadIdx.x; i < HIDDEN * N_CLASS; i += 256) sW[i] = W2[i];
    if (threadIdx.x < N_CLASS) sb[threadIdx.x] = b2[threadIdx.x];
    __syncthreads();
    int node = blockIdx.x * 256 + threadIdx.x;
    if (node >= N_NODES) return;

    float hv[HIDDEN];
    const float4* hr = reinterpret_cast<const float4*>(h + (long long)node * HIDDEN);
#pragma unroll
    for (int q = 0; q < HIDDEN / 4; ++q) {
        float4 v = hr[q];
        hv[q * 4 + 0] = v.x; hv[q * 4 + 1] = v.y;
        hv[q * 4 + 2] = v.z; hv[q * 4 + 3] = v.w;
    }
    float z[N_CLASS];
#pragma unroll
    for (int c = 0; c < N_CLASS; ++c) z[c] = sb[c];
#pragma unroll
    for (int k = 0; k < HIDDEN; ++k) {
        float hk = hv[k];
#pragma unroll
        for (int c = 0; c < N_CLASS; ++c) z[c] += hk * sW[k * N_CLASS + c];
    }
    float m = z[0];
#pragma unroll
    for (int c = 1; c < N_CLASS; ++c) m = fmaxf(m, z[c]);
    float ssum = 0.0f;
#pragma unroll
    for (int c = 0; c < N_CLASS; ++c) ssum += expf(z[c] - m);
    float l = m + logf(ssum);
    float* orow = out + (long long)node * N_CLASS;
#pragma unroll
    for (int c = 0; c < N_CLASS; ++c) orow[c] = z[c] - l;
}

static inline char* align256(char* p) {
    return (char*)(((size_t)p + 255) & ~(size_t)255);
}

extern "C" void kernel_launch(void* const* d_in, const int* in_sizes, int n_in,
                              void* d_out, int out_size, void* d_ws, size_t ws_size,
                              hipStream_t stream) {
    const float* x   = (const float*)d_in[0];
    const int*   ei  = (const int*)d_in[1];
    const float* W1  = (const float*)d_in[2];
    const float* b1  = (const float*)d_in[3];
    const float* Wc0 = (const float*)d_in[4];
    const float* bc0 = (const float*)d_in[5];
    const float* Wc1 = (const float*)d_in[6];
    const float* bc1 = (const float*)d_in[7];
    const float* W2  = (const float*)d_in[8];
    const float* b2  = (const float*)d_in[9];
    float* out = (float*)d_out;

    long long E = (long long)in_sizes[1] / 2;

    char* p = (char*)d_ws;
    int* flag      = (int*)p;            p = align256(p + sizeof(int));
    int* cnt       = (int*)p;            p = align256(p + sizeof(int) * N_NODES);
    float* dinv    = (float*)p;          p = align256(p + sizeof(float) * N_NODES);
    int* bcnt      = (int*)p;            p = align256(p + sizeof(int) * NBKT);
    int* bkt_base  = (int*)p;            p = align256(p + sizeof(int) * (NBKT + 1));
    int* gcur      = (int*)p;            p = align256(p + sizeof(int) * NBKT);
    int* pairs     = (int*)p;            p = align256(p + sizeof(int) * E);
    float* h       = (float*)p;          p = align256(p + sizeof(float) * (size_t)N_NODES * HIDDEN);
    __half* tmpp   = (__half*)p;         p = align256(p + sizeof(__half) * (size_t)N_NODES * HIDDEN);

    const int nblk_node   = (N_NODES + 255) / 256;
    const int nblk_edge   = (int)((E + 255) / 256);
    const int nblk_bucket = (int)((E + TILE - 1) / TILE);
    const int nblk_bcnt   = (NBKT + 255) / 256;

    hipMemsetAsync(cnt, 0, sizeof(int) * N_NODES, stream);
    k_detect<<<1, 1, 0, stream>>>(ei, flag);
    k_hist<<<nblk_edge, 256, 0, stream>>>(ei, E, flag, cnt);
    k_dinv<<<nblk_node, 256, 0, stream>>>(cnt, dinv);

    k_bktcnt<<<nblk_bcnt, 256, 0, stream>>>(cnt, bcnt);
    k_bktscan<<<1, 1024, 0, stream>>>(bcnt, gcur, bkt_base);
    k_bucket<<<nblk_bucket, 256, 0, stream>>>(ei, E, flag, gcur, pairs);

    k_lin1<<<nblk_node, 256, 0, stream>>>(x, W1, b1, h);

    // conv 1
    k_mm16<<<nblk_node, 256, 0, stream>>>(h, Wc0, dinv, tmpp);
    k_aggr<<<NBKT, 512, 0, stream>>>(bkt_base, pairs, tmpp, dinv, bc0, h);

    // conv 2
    k_mm16<<<nblk_node, 256, 0, stream>>>(h, Wc1, dinv, tmpp);
    k_aggr<<<NBKT, 512, 0, stream>>>(bkt_base, pairs, tmpp, dinv, bc1, h);

    k_out<<<nblk_node, 256, 0, stream>>>(h, W2, b2, out);
}

// Round 8
// 342.292 us; speedup vs baseline: 3.0284x; 2.6664x over previous
//
#include <hip/hip_runtime.h>
#include <hip/hip_fp16.h>
#include <math.h>

#define N_NODES 100000
#define F_IN    100
#define HIDDEN  16
#define N_CLASS 18

#define BKT_SHIFT 7
#define BKT_NODES 128                                   // nodes per bucket
#define NBKT ((N_NODES + BKT_NODES - 1) / BKT_NODES)    // 782
#define TILE 8192                                       // edges per k_bucket block
#define SCAN_NB ((N_NODES + 255) / 256)                 // 391
#define SORT_CAP 5120                                   // max edges per bucket (mean 4096, sigma 64)

// ---- edge dtype detector: int64 little-endian (values < 2^31) has all-zero odd int32 words
__global__ void k_detect(const int* __restrict__ ei, int* __restrict__ flag) {
    int z = 1;
    for (int i = 0; i < 16; ++i) {
        if (ei[2 * i + 1] != 0) z = 0;
    }
    *flag = z;  // 1 => int64 layout, 0 => int32 layout
}

__device__ __forceinline__ int edge_at(const int* __restrict__ ei, long long idx, int is64) {
    return is64 ? ei[2 * idx] : ei[idx];
}

// ---- per-node in-degree histogram
__global__ __launch_bounds__(256) void k_hist(const int* __restrict__ ei, long long E,
                                              const int* __restrict__ flag,
                                              int* __restrict__ cnt) {
    long long e = (long long)blockIdx.x * 256 + threadIdx.x;
    if (e >= E) return;
    int is64 = *flag;
    int d = edge_at(ei, E + e, is64);
    atomicAdd(&cnt[d], 1);
}

__global__ __launch_bounds__(256) void k_dinv(const int* __restrict__ cnt,
                                              float* __restrict__ dinv) {
    int i = blockIdx.x * 256 + threadIdx.x;
    if (i < N_NODES) dinv[i] = rsqrtf((float)cnt[i] + 1.0f);
}

// ---- 3-kernel exclusive scan over per-node cnt -> row_start (+ bucket cursors)
__global__ __launch_bounds__(256) void k_scan1(const int* __restrict__ cnt,
                                               int* __restrict__ incl,
                                               int* __restrict__ bsum) {
    __shared__ int s[256];
    int tid = threadIdx.x;
    int i = blockIdx.x * 256 + tid;
    int v = (i < N_NODES) ? cnt[i] : 0;
    s[tid] = v;
    __syncthreads();
    for (int off = 1; off < 256; off <<= 1) {
        int t = (tid >= off) ? s[tid - off] : 0;
        __syncthreads();
        s[tid] += t;
        __syncthreads();
    }
    if (i < N_NODES) incl[i] = s[tid];
    if (tid == 255) bsum[blockIdx.x] = s[255];
}

__global__ __launch_bounds__(512) void k_scan2(int* __restrict__ bsum) {
    __shared__ int s[512];
    int tid = threadIdx.x;
    int v = (tid < SCAN_NB) ? bsum[tid] : 0;
    s[tid] = v;
    __syncthreads();
    for (int off = 1; off < 512; off <<= 1) {
        int t = (tid >= off) ? s[tid - off] : 0;
        __syncthreads();
        s[tid] += t;
        __syncthreads();
    }
    if (tid < SCAN_NB) bsum[tid] = s[tid];  // inclusive
}

__global__ __launch_bounds__(256) void k_scan3(const int* __restrict__ cnt,
                                               const int* __restrict__ incl,
                                               const int* __restrict__ bsum,
                                               long long E,
                                               int* __restrict__ row_start,
                                               int* __restrict__ gcur) {
    int i = blockIdx.x * 256 + threadIdx.x;
    if (i >= N_NODES) return;
    int b = i >> 8;
    int base = (b > 0) ? bsum[b - 1] : 0;
    int rs = base + incl[i] - cnt[i];   // exclusive
    row_start[i] = rs;
    if ((i & (BKT_NODES - 1)) == 0) gcur[i >> BKT_SHIFT] = rs;
    if (i == 0) row_start[N_NODES] = (int)E;
}

// ---- level-1 split: per-tile LDS counting sort by bucket, coalesced packed writes
// pairs[pos] = src | (dst&127)<<17   (src < 2^17, dst-local 7 bits)
__global__ __launch_bounds__(256) void k_bucket(const int* __restrict__ ei, long long E,
                                                const int* __restrict__ flag,
                                                int* __restrict__ gcur,
                                                int* __restrict__ pairs) {
    __shared__ int hist[NBKT];
    __shared__ int lbase[NBKT];
    __shared__ int gbase[NBKT];
    __shared__ int lcur[NBKT];
    __shared__ unsigned short perm[TILE];
    __shared__ int ts[256];
    int tid = threadIdx.x;
    int is64 = *flag;
    long long e0 = (long long)blockIdx.x * TILE;
    int n = (int)(((E - e0) < (long long)TILE) ? (E - e0) : (long long)TILE);

    for (int i = tid; i < NBKT; i += 256) hist[i] = 0;
    __syncthreads();
    for (int i = tid; i < n; i += 256) {
        int d = edge_at(ei, E + e0 + i, is64);
        atomicAdd(&hist[d >> BKT_SHIFT], 1);
    }
    __syncthreads();

    // exclusive scan of hist into lbase; thread owns 4 consecutive buckets
    int b0 = tid * 4;
    int h0 = (b0 + 0 < NBKT) ? hist[b0 + 0] : 0;
    int h1 = (b0 + 1 < NBKT) ? hist[b0 + 1] : 0;
    int h2 = (b0 + 2 < NBKT) ? hist[b0 + 2] : 0;
    int h3 = (b0 + 3 < NBKT) ? hist[b0 + 3] : 0;
    int tsum = h0 + h1 + h2 + h3;
    ts[tid] = tsum;
    __syncthreads();
    for (int off = 1; off < 256; off <<= 1) {
        int t = (tid >= off) ? ts[tid - off] : 0;
        __syncthreads();
        ts[tid] += t;
        __syncthreads();
    }
    int eb = ts[tid] - tsum;
    if (b0 + 0 < NBKT) lbase[b0 + 0] = eb;
    if (b0 + 1 < NBKT) lbase[b0 + 1] = eb + h0;
    if (b0 + 2 < NBKT) lbase[b0 + 2] = eb + h0 + h1;
    if (b0 + 3 < NBKT) lbase[b0 + 3] = eb + h0 + h1 + h2;

    // reserve this block's run in each bucket's global region
    for (int b = tid; b < NBKT; b += 256) {
        int c = hist[b];
        gbase[b] = (c > 0) ? atomicAdd(&gcur[b], c) : 0;
    }
    __syncthreads();
    for (int i = tid; i < NBKT; i += 256) lcur[i] = lbase[i];
    __syncthreads();

    // local binning (perm holds tile-local edge ids, grouped by bucket)
    for (int i = tid; i < n; i += 256) {
        int d = edge_at(ei, E + e0 + i, is64);
        int l = atomicAdd(&lcur[d >> BKT_SHIFT], 1);
        perm[l] = (unsigned short)i;
    }
    __syncthreads();

    // write out: consecutive k within a bucket-run -> consecutive positions
    for (int k = tid; k < n; k += 256) {
        int i = perm[k];
        int s = edge_at(ei, e0 + i, is64);
        int d = edge_at(ei, E + e0 + i, is64);
        int b = d >> BKT_SHIFT;
        int pos = gbase[b] + (k - lbase[b]);
        pairs[pos] = s | ((d & (BKT_NODES - 1)) << 17);
    }
}

// ---- level-2 sort: per bucket, LDS counting-sort into exact per-node CSR slots (in place)
// after this, pairs[] holds src ids sorted by dst node (CSR order per row_start)
__global__ __launch_bounds__(256) void k_sort2(const int* __restrict__ row_start,
                                               int* __restrict__ pairs) {
    __shared__ int stage[SORT_CAP];
    __shared__ int cur[BKT_NODES];
    int bk = blockIdx.x, tid = threadIdx.x;
    int nb = bk * BKT_NODES;
    int ne = min(nb + BKT_NODES, N_NODES);
    int i0 = row_start[nb];
    int i1 = row_start[ne];
    int m = i1 - i0;
    for (int i = tid; i < m; i += 256) stage[i] = pairs[i0 + i];
    if (tid < BKT_NODES) cur[tid] = (nb + tid < N_NODES) ? row_start[nb + tid] : 0;
    __syncthreads();
    for (int i = tid; i < m; i += 256) {
        int v = stage[i];
        int pos = atomicAdd(&cur[v >> 17], 1);
        pairs[pos] = v & 0x1FFFF;
    }
}

// ---- h = relu(x @ W1 + b1)   [N,100]@[100,16]
__global__ __launch_bounds__(256) void k_lin1(const float* __restrict__ x,
                                              const float* __restrict__ W1,
                                              const float* __restrict__ b1,
                                              float* __restrict__ h) {
    __shared__ float sW[F_IN * HIDDEN];
    __shared__ float sb[HIDDEN];
    for (int i = threadIdx.x; i < F_IN * HIDDEN; i += 256) sW[i] = W1[i];
    if (threadIdx.x < HIDDEN) sb[threadIdx.x] = b1[threadIdx.x];
    __syncthreads();
    int node = blockIdx.x * 256 + threadIdx.x;
    if (node >= N_NODES) return;

    float acc[HIDDEN];
#pragma unroll
    for (int j = 0; j < HIDDEN; ++j) acc[j] = sb[j];

    const float4* x4 = reinterpret_cast<const float4*>(x + (long long)node * F_IN);
#pragma unroll 2
    for (int k4 = 0; k4 < F_IN / 4; ++k4) {
        float4 xv = x4[k4];
        const float* w = &sW[k4 * 4 * HIDDEN];
#pragma unroll
        for (int j = 0; j < HIDDEN; ++j) {
            acc[j] += xv.x * w[0 * HIDDEN + j];
            acc[j] += xv.y * w[1 * HIDDEN + j];
            acc[j] += xv.z * w[2 * HIDDEN + j];
            acc[j] += xv.w * w[3 * HIDDEN + j];
        }
    }
    float4* hr = reinterpret_cast<float4*>(h + (long long)node * HIDDEN);
#pragma unroll
    for (int q = 0; q < HIDDEN / 4; ++q) {
        float4 o;
        o.x = fmaxf(acc[q * 4 + 0], 0.0f);
        o.y = fmaxf(acc[q * 4 + 1], 0.0f);
        o.z = fmaxf(acc[q * 4 + 2], 0.0f);
        o.w = fmaxf(acc[q * 4 + 3], 0.0f);
        hr[q] = o;
    }
}

// ---- tmp' = fp16( dinv[i] * (h @ W) )   [3.2 MB table -> per-XCD-L2 resident]
__global__ __launch_bounds__(256) void k_mm16(const float* __restrict__ h,
                                              const float* __restrict__ W,
                                              const float* __restrict__ dinv,
                                              __half* __restrict__ tmpp) {
    __shared__ float sW[HIDDEN * HIDDEN];
    if (threadIdx.x < HIDDEN * HIDDEN) sW[threadIdx.x] = W[threadIdx.x];
    __syncthreads();
    int node = blockIdx.x * 256 + threadIdx.x;
    if (node >= N_NODES) return;

    float hv[HIDDEN];
    const float4* hr = reinterpret_cast<const float4*>(h + (long long)node * HIDDEN);
#pragma unroll
    for (int q = 0; q < HIDDEN / 4; ++q) {
        float4 v = hr[q];
        hv[q * 4 + 0] = v.x; hv[q * 4 + 1] = v.y;
        hv[q * 4 + 2] = v.z; hv[q * 4 + 3] = v.w;
    }
    float di = dinv[node];
    float out[HIDDEN];
#pragma unroll
    for (int j = 0; j < HIDDEN; ++j) out[j] = 0.0f;
#pragma unroll
    for (int k = 0; k < HIDDEN; ++k) {
        float hk = hv[k];
#pragma unroll
        for (int j = 0; j < HIDDEN; ++j) out[j] += hk * sW[k * HIDDEN + j];
    }
    __half2 packed[8];
#pragma unroll
    for (int j = 0; j < 8; ++j)
        packed[j] = __floats2half2_rn(di * out[2 * j], di * out[2 * j + 1]);
    float4* tp = reinterpret_cast<float4*>(tmpp + (long long)node * HIDDEN);
    const float4* ps = reinterpret_cast<const float4*>(packed);
    tp[0] = ps[0];
    tp[1] = ps[1];
}

// ---- wave-per-node register pull + shuffle reduce + fused epilogue
// h[n] = relu(dinv[n]*(sum_src tmpp[src] + tmpp[n]) + b)
// lane = 2*edge_slot + hp; hp selects the 16-B (8-half) half-row
__global__ __launch_bounds__(256) void k_aggr(const int* __restrict__ row_start,
                                              const int* __restrict__ srcs,
                                              const __half* __restrict__ tmpp,
                                              const float* __restrict__ dinv,
                                              const float* __restrict__ b,
                                              float* __restrict__ h) {
    int wave = (blockIdx.x * 256 + threadIdx.x) >> 6;   // node id
    if (wave >= N_NODES) return;
    int lane = threadIdx.x & 63;
    int es = lane >> 1;        // edge slot 0..31
    int hp = lane & 1;         // half-row select

    int s0 = row_start[wave], s1 = row_start[wave + 1];
    float acc[8];
#pragma unroll
    for (int j = 0; j < 8; ++j) acc[j] = 0.0f;

    for (int e = s0 + es; e < s1; e += 32) {
        int src = srcs[e];
        float4 rv = *(reinterpret_cast<const float4*>(
                          tmpp + (long long)src * HIDDEN) + hp);
        const __half2* h2 = reinterpret_cast<const __half2*>(&rv);
#pragma unroll
        for (int j = 0; j < 4; ++j) {
            float2 f = __half22float2(h2[j]);
            acc[2 * j + 0] += f.x;
            acc[2 * j + 1] += f.y;
        }
    }
    // reduce across edge slots (preserve hp bit 0): masks 2,4,8,16,32
#pragma unroll
    for (int m = 2; m <= 32; m <<= 1) {
#pragma unroll
        for (int j = 0; j < 8; ++j) acc[j] += __shfl_xor(acc[j], m);
    }
    if (es == 0) {   // lanes 0 (features 0-7) and 1 (features 8-15)
        float4 sv = *(reinterpret_cast<const float4*>(
                          tmpp + (long long)wave * HIDDEN) + hp);
        const __half2* s2 = reinterpret_cast<const __half2*>(&sv);
        float di = dinv[wave];
        float4 bv0 = *(reinterpret_cast<const float4*>(b) + hp * 2 + 0);
        float4 bv1 = *(reinterpret_cast<const float4*>(b) + hp * 2 + 1);
        const float* bb = reinterpret_cast<const float*>(&bv0);  // bv0,bv1 contiguous? safer below
        float bs[8];
        bs[0] = bv0.x; bs[1] = bv0.y; bs[2] = bv0.z; bs[3] = bv0.w;
        bs[4] = bv1.x; bs[5] = bv1.y; bs[6] = bv1.z; bs[7] = bv1.w;
        (void)bb;
        float o[8];
#pragma unroll
        for (int j = 0; j < 4; ++j) {
            float2 f = __half22float2(s2[j]);
            o[2 * j + 0] = fmaxf(di * (acc[2 * j + 0] + f.x) + bs[2 * j + 0], 0.0f);
            o[2 * j + 1] = fmaxf(di * (acc[2 * j + 1] + f.y) + bs[2 * j + 1], 0.0f);
        }
        float4* hw = reinterpret_cast<float4*>(h + (long long)wave * HIDDEN + hp * 8);
        float4 w0, w1;
        w0.x = o[0]; w0.y = o[1]; w0.z = o[2]; w0.w = o[3];
        w1.x = o[4]; w1.y = o[5]; w1.z = o[6]; w1.w = o[7];
        hw[0] = w0;
        hw[1] = w1;
    }
}

// ---- out = log_softmax(h @ W2 + b2)
__global__ __launch_bounds__(256) void k_out(const float* __restrict__ h,
                                             const float* __restrict__ W2,
                                             const float* __restrict__ b2,
                                             float* __restrict__ out) {
    __shared__ float sW[HIDDEN * N_CLASS];
    __shared__ float sb[N_CLASS];
    for (int i = threadIdx.x; i < HIDDEN * N_CLASS; i += 256) sW[i] = W2[i];
    if (threadIdx.x < N_CLASS) sb[threadIdx.x] = b2[threadIdx.x];
    __syncthreads();
    int node = blockIdx.x * 256 + threadIdx.x;
    if (node >= N_NODES) return;

    float hv[HIDDEN];
    const float4* hr = reinterpret_cast<const float4*>(h + (long long)node * HIDDEN);
#pragma unroll
    for (int q = 0; q < HIDDEN / 4; ++q) {
        float4 v = hr[q];
        hv[q * 4 + 0] = v.x; hv[q * 4 + 1] = v.y;
        hv[q * 4 + 2] = v.z; hv[q * 4 + 3] = v.w;
    }
    float z[N_CLASS];
#pragma unroll
    for (int c = 0; c < N_CLASS; ++c) z[c] = sb[c];
#pragma unroll
    for (int k = 0; k < HIDDEN; ++k) {
        float hk = hv[k];
#pragma unroll
        for (int c = 0; c < N_CLASS; ++c) z[c] += hk * sW[k * N_CLASS + c];
    }
    float m = z[0];
#pragma unroll
    for (int c = 1; c < N_CLASS; ++c) m = fmaxf(m, z[c]);
    float ssum = 0.0f;
#pragma unroll
    for (int c = 0; c < N_CLASS; ++c) ssum += expf(z[c] - m);
    float l = m + logf(ssum);
    float* orow = out + (long long)node * N_CLASS;
#pragma unroll
    for (int c = 0; c < N_CLASS; ++c) orow[c] = z[c] - l;
}

static inline char* align256(char* p) {
    return (char*)(((size_t)p + 255) & ~(size_t)255);
}

extern "C" void kernel_launch(void* const* d_in, const int* in_sizes, int n_in,
                              void* d_out, int out_size, void* d_ws, size_t ws_size,
                              hipStream_t stream) {
    const float* x   = (const float*)d_in[0];
    const int*   ei  = (const int*)d_in[1];
    const float* W1  = (const float*)d_in[2];
    const float* b1  = (const float*)d_in[3];
    const float* Wc0 = (const float*)d_in[4];
    const float* bc0 = (const float*)d_in[5];
    const float* Wc1 = (const float*)d_in[6];
    const float* bc1 = (const float*)d_in[7];
    const float* W2  = (const float*)d_in[8];
    const float* b2  = (const float*)d_in[9];
    float* out = (float*)d_out;

    long long E = (long long)in_sizes[1] / 2;

    char* p = (char*)d_ws;
    int* flag      = (int*)p;            p = align256(p + sizeof(int));
    int* cnt       = (int*)p;            p = align256(p + sizeof(int) * N_NODES);
    float* dinv    = (float*)p;          p = align256(p + sizeof(float) * N_NODES);
    int* row_start = (int*)p;            p = align256(p + sizeof(int) * (N_NODES + 1));
    int* bsum      = (int*)p;            p = align256(p + sizeof(int) * 512);
    int* gcur      = (int*)p;            p = align256(p + sizeof(int) * NBKT);
    int* pairs     = (int*)p;            p = align256(p + sizeof(int) * E);
    float* h       = (float*)p;          p = align256(p + sizeof(float) * (size_t)N_NODES * HIDDEN);
    __half* tmpp   = (__half*)p;         p = align256(p + sizeof(__half) * (size_t)N_NODES * HIDDEN);
    int* incl      = pairs;  // alias: incl used only before k_bucket fills pairs

    const int nblk_node   = (N_NODES + 255) / 256;
    const int nblk_edge   = (int)((E + 255) / 256);
    const int nblk_bucket = (int)((E + TILE - 1) / TILE);
    const int nblk_aggr   = (int)(((long long)N_NODES * 64 + 255) / 256);

    hipMemsetAsync(cnt, 0, sizeof(int) * N_NODES, stream);
    k_detect<<<1, 1, 0, stream>>>(ei, flag);
    k_hist<<<nblk_edge, 256, 0, stream>>>(ei, E, flag, cnt);
    k_dinv<<<nblk_node, 256, 0, stream>>>(cnt, dinv);

    k_scan1<<<SCAN_NB, 256, 0, stream>>>(cnt, incl, bsum);
    k_scan2<<<1, 512, 0, stream>>>(bsum);
    k_scan3<<<nblk_node, 256, 0, stream>>>(cnt, incl, bsum, E, row_start, gcur);

    k_bucket<<<nblk_bucket, 256, 0, stream>>>(ei, E, flag, gcur, pairs);
    k_sort2<<<NBKT, 256, 0, stream>>>(row_start, pairs);

    k_lin1<<<nblk_node, 256, 0, stream>>>(x, W1, b1, h);

    // conv 1
    k_mm16<<<nblk_node, 256, 0, stream>>>(h, Wc0, dinv, tmpp);
    k_aggr<<<nblk_aggr, 256, 0, stream>>>(row_start, pairs, tmpp, dinv, bc0, h);

    // conv 2
    k_mm16<<<nblk_node, 256, 0, stream>>>(h, Wc1, dinv, tmpp);
    k_aggr<<<nblk_aggr, 256, 0, stream>>>(row_start, pairs, tmpp, dinv, bc1, h);

    k_out<<<nblk_node, 256, 0, stream>>>(h, W2, b2, out);
}

// Round 9
// 237.198 us; speedup vs baseline: 4.3702x; 1.4431x over previous
//
#include <hip/hip_runtime.h>
#include <hip/hip_fp16.h>
#include <math.h>

#define N_NODES 100000
#define F_IN    100
#define HIDDEN  16
#define N_CLASS 18

#define BKT_SHIFT 7
#define BKT_NODES 128                                   // nodes per bucket
#define NBKT ((N_NODES + BKT_NODES - 1) / BKT_NODES)    // 782
#define TILE 8192                                       // edges per k_bucket block
#define SCAN_NB ((N_NODES + 255) / 256)                 // 391
#define SORT_CAP 5120                                   // max edges per bucket (mean 4096, sigma 64)

// ---- edge dtype detector: int64 little-endian (values < 2^31) has all-zero odd int32 words
__global__ void k_detect(const int* __restrict__ ei, int* __restrict__ flag) {
    int z = 1;
    for (int i = 0; i < 16; ++i) {
        if (ei[2 * i + 1] != 0) z = 0;
    }
    *flag = z;  // 1 => int64 layout, 0 => int32 layout
}

__device__ __forceinline__ int edge_at(const int* __restrict__ ei, long long idx, int is64) {
    return is64 ? ei[2 * idx] : ei[idx];
}

// ---- per-bucket edge counts via per-tile LDS histogram (replaces per-node k_hist)
__global__ __launch_bounds__(256) void k_bcnt(const int* __restrict__ ei, long long E,
                                              const int* __restrict__ flag,
                                              int* __restrict__ bcnt) {
    __shared__ int hist[NBKT];
    int tid = threadIdx.x;
    for (int i = tid; i < NBKT; i += 256) hist[i] = 0;
    __syncthreads();
    int is64 = *flag;
    long long e0 = (long long)blockIdx.x * TILE;
    int n = (int)(((E - e0) < (long long)TILE) ? (E - e0) : (long long)TILE);
    for (int i = tid; i < n; i += 256) {
        int d = edge_at(ei, E + e0 + i, is64);
        atomicAdd(&hist[d >> BKT_SHIFT], 1);
    }
    __syncthreads();
    for (int b = tid; b < NBKT; b += 256) {
        int c = hist[b];
        if (c) atomicAdd(&bcnt[b], c);
    }
}

// ---- single-block scan over 782 bucket counts -> bases + global cursors
__global__ __launch_bounds__(1024) void k_bktscan(const int* __restrict__ bcnt,
                                                  int* __restrict__ gcur,
                                                  int* __restrict__ bkt_base) {
    __shared__ int s[1024];
    int tid = threadIdx.x;
    int v = (tid < NBKT) ? bcnt[tid] : 0;
    s[tid] = v;
    __syncthreads();
    for (int off = 1; off < 1024; off <<= 1) {
        int t = (tid >= off) ? s[tid - off] : 0;
        __syncthreads();
        s[tid] += t;
        __syncthreads();
    }
    if (tid < NBKT) {
        int e = s[tid] - v;  // exclusive
        gcur[tid] = e;
        bkt_base[tid] = e;
    }
    if (tid == 1023) bkt_base[NBKT] = s[1023];
}

// ---- level-1 split: per-tile LDS counting sort by bucket, coalesced packed writes
// pairs[pos] = src | (dst&127)<<17   (src < 2^17, dst-local 7 bits)
__global__ __launch_bounds__(256) void k_bucket(const int* __restrict__ ei, long long E,
                                                const int* __restrict__ flag,
                                                int* __restrict__ gcur,
                                                int* __restrict__ pairs) {
    __shared__ int hist[NBKT];
    __shared__ int lbase[NBKT];
    __shared__ int gbase[NBKT];
    __shared__ int lcur[NBKT];
    __shared__ unsigned short perm[TILE];
    __shared__ int ts[256];
    int tid = threadIdx.x;
    int is64 = *flag;
    long long e0 = (long long)blockIdx.x * TILE;
    int n = (int)(((E - e0) < (long long)TILE) ? (E - e0) : (long long)TILE);

    for (int i = tid; i < NBKT; i += 256) hist[i] = 0;
    __syncthreads();
    for (int i = tid; i < n; i += 256) {
        int d = edge_at(ei, E + e0 + i, is64);
        atomicAdd(&hist[d >> BKT_SHIFT], 1);
    }
    __syncthreads();

    // exclusive scan of hist into lbase; thread owns 4 consecutive buckets
    int b0 = tid * 4;
    int h0 = (b0 + 0 < NBKT) ? hist[b0 + 0] : 0;
    int h1 = (b0 + 1 < NBKT) ? hist[b0 + 1] : 0;
    int h2 = (b0 + 2 < NBKT) ? hist[b0 + 2] : 0;
    int h3 = (b0 + 3 < NBKT) ? hist[b0 + 3] : 0;
    int tsum = h0 + h1 + h2 + h3;
    ts[tid] = tsum;
    __syncthreads();
    for (int off = 1; off < 256; off <<= 1) {
        int t = (tid >= off) ? ts[tid - off] : 0;
        __syncthreads();
        ts[tid] += t;
        __syncthreads();
    }
    int eb = ts[tid] - tsum;
    if (b0 + 0 < NBKT) lbase[b0 + 0] = eb;
    if (b0 + 1 < NBKT) lbase[b0 + 1] = eb + h0;
    if (b0 + 2 < NBKT) lbase[b0 + 2] = eb + h0 + h1;
    if (b0 + 3 < NBKT) lbase[b0 + 3] = eb + h0 + h1 + h2;

    // reserve this block's run in each bucket's global region
    for (int b = tid; b < NBKT; b += 256) {
        int c = hist[b];
        gbase[b] = (c > 0) ? atomicAdd(&gcur[b], c) : 0;
    }
    __syncthreads();
    for (int i = tid; i < NBKT; i += 256) lcur[i] = lbase[i];
    __syncthreads();

    // local binning (perm holds tile-local edge ids, grouped by bucket)
    for (int i = tid; i < n; i += 256) {
        int d = edge_at(ei, E + e0 + i, is64);
        int l = atomicAdd(&lcur[d >> BKT_SHIFT], 1);
        perm[l] = (unsigned short)i;
    }
    __syncthreads();

    // write out: consecutive k within a bucket-run -> consecutive positions
    for (int k = tid; k < n; k += 256) {
        int i = perm[k];
        int s = edge_at(ei, e0 + i, is64);
        int d = edge_at(ei, E + e0 + i, is64);
        int b = d >> BKT_SHIFT;
        int pos = gbase[b] + (k - lbase[b]);
        pairs[pos] = s | ((d & (BKT_NODES - 1)) << 17);
    }
}

// ---- per-node counts + dinv from bucket-grouped pairs (coalesced reads, LDS counters)
__global__ __launch_bounds__(256) void k_cnt(const int* __restrict__ bkt_base,
                                             const int* __restrict__ pairs,
                                             int* __restrict__ cnt,
                                             float* __restrict__ dinv) {
    __shared__ int lc[BKT_NODES];
    int bk = blockIdx.x, tid = threadIdx.x;
    if (tid < BKT_NODES) lc[tid] = 0;
    __syncthreads();
    int i0 = bkt_base[bk], i1 = bkt_base[bk + 1];
    for (int i = i0 + tid; i < i1; i += 256) {
        atomicAdd(&lc[pairs[i] >> 17], 1);
    }
    __syncthreads();
    int node = bk * BKT_NODES + tid;
    if (tid < BKT_NODES && node < N_NODES) {
        int c = lc[tid];
        cnt[node] = c;
        dinv[node] = rsqrtf((float)c + 1.0f);
    }
}

// ---- 3-kernel exclusive scan over per-node cnt -> row_start
__global__ __launch_bounds__(256) void k_scan1(const int* __restrict__ cnt,
                                               int* __restrict__ incl,
                                               int* __restrict__ bsum) {
    __shared__ int s[256];
    int tid = threadIdx.x;
    int i = blockIdx.x * 256 + tid;
    int v = (i < N_NODES) ? cnt[i] : 0;
    s[tid] = v;
    __syncthreads();
    for (int off = 1; off < 256; off <<= 1) {
        int t = (tid >= off) ? s[tid - off] : 0;
        __syncthreads();
        s[tid] += t;
        __syncthreads();
    }
    if (i < N_NODES) incl[i] = s[tid];
    if (tid == 255) bsum[blockIdx.x] = s[255];
}

__global__ __launch_bounds__(512) void k_scan2(int* __restrict__ bsum) {
    __shared__ int s[512];
    int tid = threadIdx.x;
    int v = (tid < SCAN_NB) ? bsum[tid] : 0;
    s[tid] = v;
    __syncthreads();
    for (int off = 1; off < 512; off <<= 1) {
        int t = (tid >= off) ? s[tid - off] : 0;
        __syncthreads();
        s[tid] += t;
        __syncthreads();
    }
    if (tid < SCAN_NB) bsum[tid] = s[tid];  // inclusive
}

__global__ __launch_bounds__(256) void k_scan3(const int* __restrict__ cnt,
                                               const int* __restrict__ incl,
                                               const int* __restrict__ bsum,
                                               long long E,
                                               int* __restrict__ row_start) {
    int i = blockIdx.x * 256 + threadIdx.x;
    if (i >= N_NODES) return;
    int b = i >> 8;
    int base = (b > 0) ? bsum[b - 1] : 0;
    int rs = base + incl[i] - cnt[i];   // exclusive
    row_start[i] = rs;
    if (i == 0) row_start[N_NODES] = (int)E;
}

// ---- level-2 sort: per bucket, LDS counting-sort into exact per-node CSR slots (in place)
__global__ __launch_bounds__(256) void k_sort2(const int* __restrict__ row_start,
                                               int* __restrict__ pairs) {
    __shared__ int stage[SORT_CAP];
    __shared__ int cur[BKT_NODES];
    int bk = blockIdx.x, tid = threadIdx.x;
    int nb = bk * BKT_NODES;
    int ne = min(nb + BKT_NODES, N_NODES);
    int i0 = row_start[nb];
    int i1 = row_start[ne];
    int m = i1 - i0;
    for (int i = tid; i < m; i += 256) stage[i] = pairs[i0 + i];
    if (tid < BKT_NODES) cur[tid] = (nb + tid < N_NODES) ? row_start[nb + tid] : 0;
    __syncthreads();
    for (int i = tid; i < m; i += 256) {
        int v = stage[i];
        int pos = atomicAdd(&cur[v >> 17], 1);
        pairs[pos] = v & 0x1FFFF;
    }
}

// ---- h = relu(x @ W1 + b1)   [N,100]@[100,16]
__global__ __launch_bounds__(256) void k_lin1(const float* __restrict__ x,
                                              const float* __restrict__ W1,
                                              const float* __restrict__ b1,
                                              float* __restrict__ h) {
    __shared__ float sW[F_IN * HIDDEN];
    __shared__ float sb[HIDDEN];
    for (int i = threadIdx.x; i < F_IN * HIDDEN; i += 256) sW[i] = W1[i];
    if (threadIdx.x < HIDDEN) sb[threadIdx.x] = b1[threadIdx.x];
    __syncthreads();
    int node = blockIdx.x * 256 + threadIdx.x;
    if (node >= N_NODES) return;

    float acc[HIDDEN];
#pragma unroll
    for (int j = 0; j < HIDDEN; ++j) acc[j] = sb[j];

    const float4* x4 = reinterpret_cast<const float4*>(x + (long long)node * F_IN);
#pragma unroll 2
    for (int k4 = 0; k4 < F_IN / 4; ++k4) {
        float4 xv = x4[k4];
        const float* w = &sW[k4 * 4 * HIDDEN];
#pragma unroll
        for (int j = 0; j < HIDDEN; ++j) {
            acc[j] += xv.x * w[0 * HIDDEN + j];
            acc[j] += xv.y * w[1 * HIDDEN + j];
            acc[j] += xv.z * w[2 * HIDDEN + j];
            acc[j] += xv.w * w[3 * HIDDEN + j];
        }
    }
    float4* hr = reinterpret_cast<float4*>(h + (long long)node * HIDDEN);
#pragma unroll
    for (int q = 0; q < HIDDEN / 4; ++q) {
        float4 o;
        o.x = fmaxf(acc[q * 4 + 0], 0.0f);
        o.y = fmaxf(acc[q * 4 + 1], 0.0f);
        o.z = fmaxf(acc[q * 4 + 2], 0.0f);
        o.w = fmaxf(acc[q * 4 + 3], 0.0f);
        hr[q] = o;
    }
}

// ---- tmp' = fp16( dinv[i] * (h @ W) )   [3.2 MB table -> per-XCD-L2 resident]
__global__ __launch_bounds__(256) void k_mm16(const float* __restrict__ h,
                                              const float* __restrict__ W,
                                              const float* __restrict__ dinv,
                                              __half* __restrict__ tmpp) {
    __shared__ float sW[HIDDEN * HIDDEN];
    if (threadIdx.x < HIDDEN * HIDDEN) sW[threadIdx.x] = W[threadIdx.x];
    __syncthreads();
    int node = blockIdx.x * 256 + threadIdx.x;
    if (node >= N_NODES) return;

    float hv[HIDDEN];
    const float4* hr = reinterpret_cast<const float4*>(h + (long long)node * HIDDEN);
#pragma unroll
    for (int q = 0; q < HIDDEN / 4; ++q) {
        float4 v = hr[q];
        hv[q * 4 + 0] = v.x; hv[q * 4 + 1] = v.y;
        hv[q * 4 + 2] = v.z; hv[q * 4 + 3] = v.w;
    }
    float di = dinv[node];
    float out[HIDDEN];
#pragma unroll
    for (int j = 0; j < HIDDEN; ++j) out[j] = 0.0f;
#pragma unroll
    for (int k = 0; k < HIDDEN; ++k) {
        float hk = hv[k];
#pragma unroll
        for (int j = 0; j < HIDDEN; ++j) out[j] += hk * sW[k * HIDDEN + j];
    }
    __half2 packed[8];
#pragma unroll
    for (int j = 0; j < 8; ++j)
        packed[j] = __floats2half2_rn(di * out[2 * j], di * out[2 * j + 1]);
    float4* tp = reinterpret_cast<float4*>(tmpp + (long long)node * HIDDEN);
    const float4* ps = reinterpret_cast<const float4*>(packed);
    tp[0] = ps[0];
    tp[1] = ps[1];
}

// ---- wave-per-node register pull + shuffle reduce + fused epilogue
// h[n] = relu(dinv[n]*(sum_src tmpp[src] + tmpp[n]) + b)
__global__ __launch_bounds__(256) void k_aggr(const int* __restrict__ row_start,
                                              const int* __restrict__ srcs,
                                              const __half* __restrict__ tmpp,
                                              const float* __restrict__ dinv,
                                              const float* __restrict__ b,
                                              float* __restrict__ h) {
    int wave = (blockIdx.x * 256 + threadIdx.x) >> 6;   // node id
    if (wave >= N_NODES) return;
    int lane = threadIdx.x & 63;
    int es = lane >> 1;        // edge slot 0..31
    int hp = lane & 1;         // half-row select

    int s0 = row_start[wave], s1 = row_start[wave + 1];
    float acc[8];
#pragma unroll
    for (int j = 0; j < 8; ++j) acc[j] = 0.0f;

    for (int e = s0 + es; e < s1; e += 32) {
        int src = srcs[e];
        float4 rv = *(reinterpret_cast<const float4*>(
                          tmpp + (long long)src * HIDDEN) + hp);
        const __half2* h2 = reinterpret_cast<const __half2*>(&rv);
#pragma unroll
        for (int j = 0; j < 4; ++j) {
            float2 f = __half22float2(h2[j]);
            acc[2 * j + 0] += f.x;
            acc[2 * j + 1] += f.y;
        }
    }
    // reduce across edge slots (preserve hp bit 0): masks 2,4,8,16,32
#pragma unroll
    for (int m = 2; m <= 32; m <<= 1) {
#pragma unroll
        for (int j = 0; j < 8; ++j) acc[j] += __shfl_xor(acc[j], m);
    }
    if (es == 0) {   // lanes 0 (features 0-7) and 1 (features 8-15)
        float4 sv = *(reinterpret_cast<const float4*>(
                          tmpp + (long long)wave * HIDDEN) + hp);
        const __half2* s2 = reinterpret_cast<const __half2*>(&sv);
        float di = dinv[wave];
        const float* bb = b + hp * 8;
        float o[8];
#pragma unroll
        for (int j = 0; j < 4; ++j) {
            float2 f = __half22float2(s2[j]);
            o[2 * j + 0] = fmaxf(di * (acc[2 * j + 0] + f.x) + bb[2 * j + 0], 0.0f);
            o[2 * j + 1] = fmaxf(di * (acc[2 * j + 1] + f.y) + bb[2 * j + 1], 0.0f);
        }
        float4* hw = reinterpret_cast<float4*>(h + (long long)wave * HIDDEN + hp * 8);
        float4 w0, w1;
        w0.x = o[0]; w0.y = o[1]; w0.z = o[2]; w0.w = o[3];
        w1.x = o[4]; w1.y = o[5]; w1.z = o[6]; w1.w = o[7];
        hw[0] = w0;
        hw[1] = w1;
    }
}

// ---- out = log_softmax(h @ W2 + b2)
__global__ __launch_bounds__(256) void k_out(const float* __restrict__ h,
                                             const float* __restrict__ W2,
                                             const float* __restrict__ b2,
                                             float* __restrict__ out) {
    __shared__ float sW[HIDDEN * N_CLASS];
    __shared__ float sb[N_CLASS];
    for (int i = threadIdx.x; i < HIDDEN * N_CLASS; i += 256) sW[i] = W2[i];
    if (threadIdx.x < N_CLASS) sb[threadIdx.x] = b2[threadIdx.x];
    __syncthreads();
    int node = blockIdx.x * 256 + threadIdx.x;
    if (node >= N_NODES) return;

    float hv[HIDDEN];
    const float4* hr = reinterpret_cast<const float4*>(h + (long long)node * HIDDEN);
#pragma unroll
    for (int q = 0; q < HIDDEN / 4; ++q) {
        float4 v = hr[q];
        hv[q * 4 + 0] = v.x; hv[q * 4 + 1] = v.y;
        hv[q * 4 + 2] = v.z; hv[q * 4 + 3] = v.w;
    }
    float z[N_CLASS];
#pragma unroll
    for (int c = 0; c < N_CLASS; ++c) z[c] = sb[c];
#pragma unroll
    for (int k = 0; k < HIDDEN; ++k) {
        float hk = hv[k];
#pragma unroll
        for (int c = 0; c < N_CLASS; ++c) z[c] += hk * sW[k * N_CLASS + c];
    }
    float m = z[0];
#pragma unroll
    for (int c = 1; c < N_CLASS; ++c) m = fmaxf(m, z[c]);
    float ssum = 0.0f;
#pragma unroll
    for (int c = 0; c < N_CLASS; ++c) ssum += expf(z[c] - m);
    float l = m + logf(ssum);
    float* orow = out + (long long)node * N_CLASS;
#pragma unroll
    for (int c = 0; c < N_CLASS; ++c) orow[c] = z[c] - l;
}

static inline char* align256(char* p) {
    return (char*)(((size_t)p + 255) & ~(size_t)255);
}

extern "C" void kernel_launch(void* const* d_in, const int* in_sizes, int n_in,
                              void* d_out, int out_size, void* d_ws, size_t ws_size,
                              hipStream_t stream) {
    const float* x   = (const float*)d_in[0];
    const int*   ei  = (const int*)d_in[1];
    const float* W1  = (const float*)d_in[2];
    const float* b1  = (const float*)d_in[3];
    const float* Wc0 = (const float*)d_in[4];
    const float* bc0 = (const float*)d_in[5];
    const float* Wc1 = (const float*)d_in[6];
    const float* bc1 = (const float*)d_in[7];
    const float* W2  = (const float*)d_in[8];
    const float* b2  = (const float*)d_in[9];
    float* out = (float*)d_out;

    long long E = (long long)in_sizes[1] / 2;

    char* p = (char*)d_ws;
    int* flag      = (int*)p;            p = align256(p + sizeof(int));
    int* cnt       = (int*)p;            p = align256(p + sizeof(int) * N_NODES);
    int* incl      = (int*)p;            p = align256(p + sizeof(int) * N_NODES);
    float* dinv    = (float*)p;          p = align256(p + sizeof(float) * N_NODES);
    int* row_start = (int*)p;            p = align256(p + sizeof(int) * (N_NODES + 1));
    int* bsum      = (int*)p;            p = align256(p + sizeof(int) * 512);
    int* bcnt      = (int*)p;            p = align256(p + sizeof(int) * NBKT);
    int* bkt_base  = (int*)p;            p = align256(p + sizeof(int) * (NBKT + 1));
    int* gcur      = (int*)p;            p = align256(p + sizeof(int) * NBKT);
    int* pairs     = (int*)p;            p = align256(p + sizeof(int) * E);
    float* h       = (float*)p;          p = align256(p + sizeof(float) * (size_t)N_NODES * HIDDEN);
    __half* tmpp   = (__half*)p;         p = align256(p + sizeof(__half) * (size_t)N_NODES * HIDDEN);

    const int nblk_node   = (N_NODES + 255) / 256;
    const int nblk_bucket = (int)((E + TILE - 1) / TILE);
    const int nblk_aggr   = (int)(((long long)N_NODES * 64 + 255) / 256);

    hipMemsetAsync(bcnt, 0, sizeof(int) * NBKT, stream);
    k_detect<<<1, 1, 0, stream>>>(ei, flag);

    k_bcnt<<<nblk_bucket, 256, 0, stream>>>(ei, E, flag, bcnt);
    k_bktscan<<<1, 1024, 0, stream>>>(bcnt, gcur, bkt_base);
    k_bucket<<<nblk_bucket, 256, 0, stream>>>(ei, E, flag, gcur, pairs);
    k_cnt<<<NBKT, 256, 0, stream>>>(bkt_base, pairs, cnt, dinv);

    k_scan1<<<SCAN_NB, 256, 0, stream>>>(cnt, incl, bsum);
    k_scan2<<<1, 512, 0, stream>>>(bsum);
    k_scan3<<<nblk_node, 256, 0, stream>>>(cnt, incl, bsum, E, row_start);
    k_sort2<<<NBKT, 256, 0, stream>>>(row_start, pairs);

    k_lin1<<<nblk_node, 256, 0, stream>>>(x, W1, b1, h);

    // conv 1
    k_mm16<<<nblk_node, 256, 0, stream>>>(h, Wc0, dinv, tmpp);
    k_aggr<<<nblk_aggr, 256, 0, stream>>>(row_start, pairs, tmpp, dinv, bc0, h);

    // conv 2
    k_mm16<<<nblk_node, 256, 0, stream>>>(h, Wc1, dinv, tmpp);
    k_aggr<<<nblk_aggr, 256, 0, stream>>>(row_start, pairs, tmpp, dinv, bc1, h);

    k_out<<<nblk_node, 256, 0, stream>>>(h, W2, b2, out);
}

// Round 10
// 212.174 us; speedup vs baseline: 4.8856x; 1.1179x over previous
//
#include <hip/hip_runtime.h>
#include <hip/hip_fp16.h>
#include <math.h>

#define N_NODES 100000
#define F_IN    100
#define HIDDEN  16
#define N_CLASS 18

#define BKT_SHIFT 7
#define BKT_NODES 128                                   // nodes per bucket
#define NBKT ((N_NODES + BKT_NODES - 1) / BKT_NODES)    // 782
#define TILE 8192                                       // edges per bucket-split block
#define SORT_CAP 5120                                   // max edges per bucket (mean 4090, ~16 sigma)

// ---- inline edge dtype detection: int64 little-endian (values < 2^31) has all-zero odd words
__device__ __forceinline__ int detect64(const int* __restrict__ ei) {
    int z = 1;
#pragma unroll
    for (int i = 0; i < 16; ++i)
        if (ei[2 * i + 1] != 0) z = 0;
    return z;
}

__device__ __forceinline__ int edge_at(const int* __restrict__ ei, long long idx, int is64) {
    return is64 ? ei[2 * idx] : ei[idx];
}

// ---- per-bucket edge counts via per-tile LDS histogram
__global__ __launch_bounds__(512) void k_bcnt(const int* __restrict__ ei, long long E,
                                              int* __restrict__ bcnt) {
    __shared__ int hist[NBKT];
    int tid = threadIdx.x;
    for (int i = tid; i < NBKT; i += 512) hist[i] = 0;
    __syncthreads();
    int is64 = detect64(ei);
    long long e0 = (long long)blockIdx.x * TILE;
    int n = (int)(((E - e0) < (long long)TILE) ? (E - e0) : (long long)TILE);
    for (int i = tid; i < n; i += 512) {
        int d = edge_at(ei, E + e0 + i, is64);
        atomicAdd(&hist[d >> BKT_SHIFT], 1);
    }
    __syncthreads();
    for (int b = tid; b < NBKT; b += 512) {
        int c = hist[b];
        if (c) atomicAdd(&bcnt[b], c);
    }
}

// ---- single-block scan over 782 bucket counts -> bases + global cursors
__global__ __launch_bounds__(1024) void k_bktscan(const int* __restrict__ bcnt,
                                                  int* __restrict__ gcur,
                                                  int* __restrict__ bkt_base) {
    __shared__ int s[1024];
    int tid = threadIdx.x;
    int v = (tid < NBKT) ? bcnt[tid] : 0;
    s[tid] = v;
    __syncthreads();
    for (int off = 1; off < 1024; off <<= 1) {
        int t = (tid >= off) ? s[tid - off] : 0;
        __syncthreads();
        s[tid] += t;
        __syncthreads();
    }
    if (tid < NBKT) {
        int e = s[tid] - v;  // exclusive
        gcur[tid] = e;
        bkt_base[tid] = e;
    }
    if (tid == 1023) bkt_base[NBKT] = s[1023];
}

// ---- level-1 split: per-tile LDS counting sort by bucket, coalesced packed writes
// pairs[pos] = src | (dst&127)<<17   (src < 2^17, dst-local 7 bits)
__global__ __launch_bounds__(512) void k_bucket(const int* __restrict__ ei, long long E,
                                                int* __restrict__ gcur,
                                                int* __restrict__ pairs) {
    __shared__ int hist[NBKT];
    __shared__ int lbase[NBKT];
    __shared__ int gbase[NBKT];
    __shared__ int lcur[NBKT];
    __shared__ unsigned short perm[TILE];
    __shared__ int ts[512];
    int tid = threadIdx.x;
    int is64 = detect64(ei);
    long long e0 = (long long)blockIdx.x * TILE;
    int n = (int)(((E - e0) < (long long)TILE) ? (E - e0) : (long long)TILE);

    for (int i = tid; i < NBKT; i += 512) hist[i] = 0;
    __syncthreads();
    for (int i = tid; i < n; i += 512) {
        int d = edge_at(ei, E + e0 + i, is64);
        atomicAdd(&hist[d >> BKT_SHIFT], 1);
    }
    __syncthreads();

    // exclusive scan of hist into lbase; thread owns 2 consecutive buckets
    int b0 = tid * 2;
    int h0 = (b0 + 0 < NBKT) ? hist[b0 + 0] : 0;
    int h1 = (b0 + 1 < NBKT) ? hist[b0 + 1] : 0;
    int tsum = h0 + h1;
    ts[tid] = tsum;
    __syncthreads();
    for (int off = 1; off < 512; off <<= 1) {
        int t = (tid >= off) ? ts[tid - off] : 0;
        __syncthreads();
        ts[tid] += t;
        __syncthreads();
    }
    int eb = ts[tid] - tsum;
    if (b0 + 0 < NBKT) lbase[b0 + 0] = eb;
    if (b0 + 1 < NBKT) lbase[b0 + 1] = eb + h0;

    // reserve this block's run in each bucket's global region
    for (int b = tid; b < NBKT; b += 512) {
        int c = hist[b];
        gbase[b] = (c > 0) ? atomicAdd(&gcur[b], c) : 0;
    }
    __syncthreads();
    for (int i = tid; i < NBKT; i += 512) lcur[i] = lbase[i];
    __syncthreads();

    // local binning (perm holds tile-local edge ids, grouped by bucket)
    for (int i = tid; i < n; i += 512) {
        int d = edge_at(ei, E + e0 + i, is64);
        int l = atomicAdd(&lcur[d >> BKT_SHIFT], 1);
        perm[l] = (unsigned short)i;
    }
    __syncthreads();

    // write out: consecutive k within a bucket-run -> consecutive positions
    for (int k = tid; k < n; k += 512) {
        int i = perm[k];
        int s = edge_at(ei, e0 + i, is64);
        int d = edge_at(ei, E + e0 + i, is64);
        int b = d >> BKT_SHIFT;
        int pos = gbase[b] + (k - lbase[b]);
        pairs[pos] = s | ((d & (BKT_NODES - 1)) << 17);
    }
}

// ---- fused CSR finalize: per bucket -> per-node counts, dinv, row_start, in-place sort
// (replaces k_cnt + 3-kernel global scan + k_sort2: row_start = bkt_base[bk] + local prefix)
__global__ __launch_bounds__(256) void k_csr(const int* __restrict__ bkt_base,
                                             int* __restrict__ pairs,
                                             int* __restrict__ row_start,
                                             float* __restrict__ dinv) {
    __shared__ int stage[SORT_CAP];
    __shared__ int lc[BKT_NODES];
    __shared__ int rs[BKT_NODES];
    int bk = blockIdx.x, tid = threadIdx.x;
    int i0 = bkt_base[bk], i1 = bkt_base[bk + 1];
    int m = i1 - i0;
    if (tid < BKT_NODES) lc[tid] = 0;
    __syncthreads();
    for (int i = tid; i < m; i += 256) {
        int v = pairs[i0 + i];
        stage[i] = v;
        atomicAdd(&lc[v >> 17], 1);
    }
    __syncthreads();
    if (tid < BKT_NODES) rs[tid] = lc[tid];
    __syncthreads();
    for (int off = 1; off < BKT_NODES; off <<= 1) {
        int t = (tid >= off && tid < BKT_NODES) ? rs[tid - off] : 0;
        __syncthreads();
        if (tid < BKT_NODES) rs[tid] += t;
        __syncthreads();
    }
    int node = bk * BKT_NODES + tid;
    int ex = 0;
    if (tid < BKT_NODES) {
        int c = lc[tid];
        ex = rs[tid] - c;          // exclusive local prefix
        if (node < N_NODES) {
            row_start[node] = i0 + ex;
            dinv[node] = rsqrtf((float)c + 1.0f);
        }
    }
    if (bk == NBKT - 1 && tid == 0) row_start[N_NODES] = i1;
    __syncthreads();
    if (tid < BKT_NODES) lc[tid] = ex;   // reuse as cursor
    __syncthreads();
    for (int i = tid; i < m; i += 256) {
        int v = stage[i];
        int pos = atomicAdd(&lc[v >> 17], 1);
        pairs[i0 + pos] = v & 0x1FFFF;
    }
}

// ---- h = relu(x @ W1 + b1)   [N,100]@[100,16]
__global__ __launch_bounds__(256) void k_lin1(const float* __restrict__ x,
                                              const float* __restrict__ W1,
                                              const float* __restrict__ b1,
                                              float* __restrict__ h) {
    __shared__ float sW[F_IN * HIDDEN];
    __shared__ float sb[HIDDEN];
    for (int i = threadIdx.x; i < F_IN * HIDDEN; i += 256) sW[i] = W1[i];
    if (threadIdx.x < HIDDEN) sb[threadIdx.x] = b1[threadIdx.x];
    __syncthreads();
    int node = blockIdx.x * 256 + threadIdx.x;
    if (node >= N_NODES) return;

    float acc[HIDDEN];
#pragma unroll
    for (int j = 0; j < HIDDEN; ++j) acc[j] = sb[j];

    const float4* x4 = reinterpret_cast<const float4*>(x + (long long)node * F_IN);
#pragma unroll 2
    for (int k4 = 0; k4 < F_IN / 4; ++k4) {
        float4 xv = x4[k4];
        const float* w = &sW[k4 * 4 * HIDDEN];
#pragma unroll
        for (int j = 0; j < HIDDEN; ++j) {
            acc[j] += xv.x * w[0 * HIDDEN + j];
            acc[j] += xv.y * w[1 * HIDDEN + j];
            acc[j] += xv.z * w[2 * HIDDEN + j];
            acc[j] += xv.w * w[3 * HIDDEN + j];
        }
    }
    float4* hr = reinterpret_cast<float4*>(h + (long long)node * HIDDEN);
#pragma unroll
    for (int q = 0; q < HIDDEN / 4; ++q) {
        float4 o;
        o.x = fmaxf(acc[q * 4 + 0], 0.0f);
        o.y = fmaxf(acc[q * 4 + 1], 0.0f);
        o.z = fmaxf(acc[q * 4 + 2], 0.0f);
        o.w = fmaxf(acc[q * 4 + 3], 0.0f);
        hr[q] = o;
    }
}

// ---- tmp' = fp16( dinv[i] * (h @ W) )   [3.2 MB table -> per-XCD-L2 resident]
__global__ __launch_bounds__(256) void k_mm16(const float* __restrict__ h,
                                              const float* __restrict__ W,
                                              const float* __restrict__ dinv,
                                              __half* __restrict__ tmpp) {
    __shared__ float sW[HIDDEN * HIDDEN];
    if (threadIdx.x < HIDDEN * HIDDEN) sW[threadIdx.x] = W[threadIdx.x];
    __syncthreads();
    int node = blockIdx.x * 256 + threadIdx.x;
    if (node >= N_NODES) return;

    float hv[HIDDEN];
    const float4* hr = reinterpret_cast<const float4*>(h + (long long)node * HIDDEN);
#pragma unroll
    for (int q = 0; q < HIDDEN / 4; ++q) {
        float4 v = hr[q];
        hv[q * 4 + 0] = v.x; hv[q * 4 + 1] = v.y;
        hv[q * 4 + 2] = v.z; hv[q * 4 + 3] = v.w;
    }
    float di = dinv[node];
    float out[HIDDEN];
#pragma unroll
    for (int j = 0; j < HIDDEN; ++j) out[j] = 0.0f;
#pragma unroll
    for (int k = 0; k < HIDDEN; ++k) {
        float hk = hv[k];
#pragma unroll
        for (int j = 0; j < HIDDEN; ++j) out[j] += hk * sW[k * HIDDEN + j];
    }
    __half2 packed[8];
#pragma unroll
    for (int j = 0; j < 8; ++j)
        packed[j] = __floats2half2_rn(di * out[2 * j], di * out[2 * j + 1]);
    float4* tp = reinterpret_cast<float4*>(tmpp + (long long)node * HIDDEN);
    const float4* ps = reinterpret_cast<const float4*>(packed);
    tp[0] = ps[0];
    tp[1] = ps[1];
}

// ---- wave-per-node register pull + shuffle reduce + fused epilogue
// h[n] = relu(dinv[n]*(sum_src tmpp[src] + tmpp[n]) + b)
__global__ __launch_bounds__(256) void k_aggr(const int* __restrict__ row_start,
                                              const int* __restrict__ srcs,
                                              const __half* __restrict__ tmpp,
                                              const float* __restrict__ dinv,
                                              const float* __restrict__ b,
                                              float* __restrict__ h) {
    int wave = (blockIdx.x * 256 + threadIdx.x) >> 6;   // node id
    if (wave >= N_NODES) return;
    int lane = threadIdx.x & 63;
    int es = lane >> 1;        // edge slot 0..31
    int hp = lane & 1;         // half-row select

    int s0 = row_start[wave], s1 = row_start[wave + 1];
    float acc[8];
#pragma unroll
    for (int j = 0; j < 8; ++j) acc[j] = 0.0f;

    for (int e = s0 + es; e < s1; e += 32) {
        int src = srcs[e];
        float4 rv = *(reinterpret_cast<const float4*>(
                          tmpp + (long long)src * HIDDEN) + hp);
        const __half2* h2 = reinterpret_cast<const __half2*>(&rv);
#pragma unroll
        for (int j = 0; j < 4; ++j) {
            float2 f = __half22float2(h2[j]);
            acc[2 * j + 0] += f.x;
            acc[2 * j + 1] += f.y;
        }
    }
    // reduce across edge slots (preserve hp bit 0): masks 2,4,8,16,32
#pragma unroll
    for (int m = 2; m <= 32; m <<= 1) {
#pragma unroll
        for (int j = 0; j < 8; ++j) acc[j] += __shfl_xor(acc[j], m);
    }
    if (es == 0) {   // lanes 0 (features 0-7) and 1 (features 8-15)
        float4 sv = *(reinterpret_cast<const float4*>(
                          tmpp + (long long)wave * HIDDEN) + hp);
        const __half2* s2 = reinterpret_cast<const __half2*>(&sv);
        float di = dinv[wave];
        const float* bb = b + hp * 8;
        float o[8];
#pragma unroll
        for (int j = 0; j < 4; ++j) {
            float2 f = __half22float2(s2[j]);
            o[2 * j + 0] = fmaxf(di * (acc[2 * j + 0] + f.x) + bb[2 * j + 0], 0.0f);
            o[2 * j + 1] = fmaxf(di * (acc[2 * j + 1] + f.y) + bb[2 * j + 1], 0.0f);
        }
        float4* hw = reinterpret_cast<float4*>(h + (long long)wave * HIDDEN + hp * 8);
        float4 w0, w1;
        w0.x = o[0]; w0.y = o[1]; w0.z = o[2]; w0.w = o[3];
        w1.x = o[4]; w1.y = o[5]; w1.z = o[6]; w1.w = o[7];
        hw[0] = w0;
        hw[1] = w1;
    }
}

// ---- out = log_softmax(h @ W2 + b2)
__global__ __launch_bounds__(256) void k_out(const float* __restrict__ h,
                                             const float* __restrict__ W2,
                                             const float* __restrict__ b2,
                                             float* __restrict__ out) {
    __shared__ float sW[HIDDEN * N_CLASS];
    __shared__ float sb[N_CLASS];
    for (int i = threadIdx.x; i < HIDDEN * N_CLASS; i += 256) sW[i] = W2[i];
    if (threadIdx.x < N_CLASS) sb[threadIdx.x] = b2[threadIdx.x];
    __syncthreads();
    int node = blockIdx.x * 256 + threadIdx.x;
    if (node >= N_NODES) return;

    float hv[HIDDEN];
    const float4* hr = reinterpret_cast<const float4*>(h + (long long)node * HIDDEN);
#pragma unroll
    for (int q = 0; q < HIDDEN / 4; ++q) {
        float4 v = hr[q];
        hv[q * 4 + 0] = v.x; hv[q * 4 + 1] = v.y;
        hv[q * 4 + 2] = v.z; hv[q * 4 + 3] = v.w;
    }
    float z[N_CLASS];
#pragma unroll
    for (int c = 0; c < N_CLASS; ++c) z[c] = sb[c];
#pragma unroll
    for (int k = 0; k < HIDDEN; ++k) {
        float hk = hv[k];
#pragma unroll
        for (int c = 0; c < N_CLASS; ++c) z[c] += hk * sW[k * N_CLASS + c];
    }
    float m = z[0];
#pragma unroll
    for (int c = 1; c < N_CLASS; ++c) m = fmaxf(m, z[c]);
    float ssum = 0.0f;
#pragma unroll
    for (int c = 0; c < N_CLASS; ++c) ssum += expf(z[c] - m);
    float l = m + logf(ssum);
    float* orow = out + (long long)node * N_CLASS;
#pragma unroll
    for (int c = 0; c < N_CLASS; ++c) orow[c] = z[c] - l;
}

static inline char* align256(char* p) {
    return (char*)(((size_t)p + 255) & ~(size_t)255);
}

extern "C" void kernel_launch(void* const* d_in, const int* in_sizes, int n_in,
                              void* d_out, int out_size, void* d_ws, size_t ws_size,
                              hipStream_t stream) {
    const float* x   = (const float*)d_in[0];
    const int*   ei  = (const int*)d_in[1];
    const float* W1  = (const float*)d_in[2];
    const float* b1  = (const float*)d_in[3];
    const float* Wc0 = (const float*)d_in[4];
    const float* bc0 = (const float*)d_in[5];
    const float* Wc1 = (const float*)d_in[6];
    const float* bc1 = (const float*)d_in[7];
    const float* W2  = (const float*)d_in[8];
    const float* b2  = (const float*)d_in[9];
    float* out = (float*)d_out;

    long long E = (long long)in_sizes[1] / 2;

    char* p = (char*)d_ws;
    float* dinv    = (float*)p;          p = align256(p + sizeof(float) * N_NODES);
    int* row_start = (int*)p;            p = align256(p + sizeof(int) * (N_NODES + 1));
    int* bcnt      = (int*)p;            p = align256(p + sizeof(int) * NBKT);
    int* bkt_base  = (int*)p;            p = align256(p + sizeof(int) * (NBKT + 1));
    int* gcur      = (int*)p;            p = align256(p + sizeof(int) * NBKT);
    int* pairs     = (int*)p;            p = align256(p + sizeof(int) * E);
    float* h       = (float*)p;          p = align256(p + sizeof(float) * (size_t)N_NODES * HIDDEN);
    __half* tmpp   = (__half*)p;         p = align256(p + sizeof(__half) * (size_t)N_NODES * HIDDEN);

    const int nblk_node   = (N_NODES + 255) / 256;
    const int nblk_bucket = (int)((E + TILE - 1) / TILE);
    const int nblk_aggr   = (int)(((long long)N_NODES * 64 + 255) / 256);

    hipMemsetAsync(bcnt, 0, sizeof(int) * NBKT, stream);

    k_bcnt<<<nblk_bucket, 512, 0, stream>>>(ei, E, bcnt);
    k_bktscan<<<1, 1024, 0, stream>>>(bcnt, gcur, bkt_base);
    k_bucket<<<nblk_bucket, 512, 0, stream>>>(ei, E, gcur, pairs);
    k_csr<<<NBKT, 256, 0, stream>>>(bkt_base, pairs, row_start, dinv);

    k_lin1<<<nblk_node, 256, 0, stream>>>(x, W1, b1, h);

    // conv 1
    k_mm16<<<nblk_node, 256, 0, stream>>>(h, Wc0, dinv, tmpp);
    k_aggr<<<nblk_aggr, 256, 0, stream>>>(row_start, pairs, tmpp, dinv, bc0, h);

    // conv 2
    k_mm16<<<nblk_node, 256, 0, stream>>>(h, Wc1, dinv, tmpp);
    k_aggr<<<nblk_aggr, 256, 0, stream>>>(row_start, pairs, tmpp, dinv, bc1, h);

    k_out<<<nblk_node, 256, 0, stream>>>(h, W2, b2, out);
}

// Round 11
// 198.442 us; speedup vs baseline: 5.2237x; 1.0692x over previous
//
#include <hip/hip_runtime.h>
#include <hip/hip_fp16.h>
#include <math.h>

#define N_NODES 100000
#define F_IN    100
#define HIDDEN  16
#define N_CLASS 18

#define BKT_SHIFT 7
#define BKT_NODES 128                                   // nodes per bucket
#define NBKT ((N_NODES + BKT_NODES - 1) / BKT_NODES)    // 782
#define TILE 8192                                       // edges per bucket-split block
#define SORT_CAP 5120                                   // max edges per bucket (mean 4090, ~16 sigma)

// ---- inline edge dtype detection: int64 little-endian (values < 2^31) has all-zero odd words
__device__ __forceinline__ int detect64(const int* __restrict__ ei) {
    int z = 1;
#pragma unroll
    for (int i = 0; i < 16; ++i)
        if (ei[2 * i + 1] != 0) z = 0;
    return z;
}

__device__ __forceinline__ int edge_at(const int* __restrict__ ei, long long idx, int is64) {
    return is64 ? ei[2 * idx] : ei[idx];
}

// ---- per-bucket edge counts via per-tile LDS histogram
__global__ __launch_bounds__(512) void k_bcnt(const int* __restrict__ ei, long long E,
                                              int* __restrict__ bcnt) {
    __shared__ int hist[NBKT];
    int tid = threadIdx.x;
    for (int i = tid; i < NBKT; i += 512) hist[i] = 0;
    __syncthreads();
    int is64 = detect64(ei);
    long long e0 = (long long)blockIdx.x * TILE;
    int n = (int)(((E - e0) < (long long)TILE) ? (E - e0) : (long long)TILE);
    for (int i = tid; i < n; i += 512) {
        int d = edge_at(ei, E + e0 + i, is64);
        atomicAdd(&hist[d >> BKT_SHIFT], 1);
    }
    __syncthreads();
    for (int b = tid; b < NBKT; b += 512) {
        int c = hist[b];
        if (c) atomicAdd(&bcnt[b], c);
    }
}

// ---- single-block scan over 782 bucket counts -> bases + global cursors
__global__ __launch_bounds__(1024) void k_bktscan(const int* __restrict__ bcnt,
                                                  int* __restrict__ gcur,
                                                  int* __restrict__ bkt_base) {
    __shared__ int s[1024];
    int tid = threadIdx.x;
    int v = (tid < NBKT) ? bcnt[tid] : 0;
    s[tid] = v;
    __syncthreads();
    for (int off = 1; off < 1024; off <<= 1) {
        int t = (tid >= off) ? s[tid - off] : 0;
        __syncthreads();
        s[tid] += t;
        __syncthreads();
    }
    if (tid < NBKT) {
        int e = s[tid] - v;  // exclusive
        gcur[tid] = e;
        bkt_base[tid] = e;
    }
    if (tid == 1023) bkt_base[NBKT] = s[1023];
}

// ---- level-1 split: per-tile LDS counting sort by bucket, coalesced packed writes
// pairs[pos] = src | (dst&127)<<17   (src < 2^17, dst-local 7 bits)
__global__ __launch_bounds__(512) void k_bucket(const int* __restrict__ ei, long long E,
                                                int* __restrict__ gcur,
                                                int* __restrict__ pairs) {
    __shared__ int hist[NBKT];
    __shared__ int lbase[NBKT];
    __shared__ int gbase[NBKT];
    __shared__ int lcur[NBKT];
    __shared__ unsigned short perm[TILE];
    __shared__ int ts[512];
    int tid = threadIdx.x;
    int is64 = detect64(ei);
    long long e0 = (long long)blockIdx.x * TILE;
    int n = (int)(((E - e0) < (long long)TILE) ? (E - e0) : (long long)TILE);

    for (int i = tid; i < NBKT; i += 512) hist[i] = 0;
    __syncthreads();
    for (int i = tid; i < n; i += 512) {
        int d = edge_at(ei, E + e0 + i, is64);
        atomicAdd(&hist[d >> BKT_SHIFT], 1);
    }
    __syncthreads();

    // exclusive scan of hist into lbase; thread owns 2 consecutive buckets
    int b0 = tid * 2;
    int h0 = (b0 + 0 < NBKT) ? hist[b0 + 0] : 0;
    int h1 = (b0 + 1 < NBKT) ? hist[b0 + 1] : 0;
    int tsum = h0 + h1;
    ts[tid] = tsum;
    __syncthreads();
    for (int off = 1; off < 512; off <<= 1) {
        int t = (tid >= off) ? ts[tid - off] : 0;
        __syncthreads();
        ts[tid] += t;
        __syncthreads();
    }
    int eb = ts[tid] - tsum;
    if (b0 + 0 < NBKT) lbase[b0 + 0] = eb;
    if (b0 + 1 < NBKT) lbase[b0 + 1] = eb + h0;

    // reserve this block's run in each bucket's global region
    for (int b = tid; b < NBKT; b += 512) {
        int c = hist[b];
        gbase[b] = (c > 0) ? atomicAdd(&gcur[b], c) : 0;
    }
    __syncthreads();
    for (int i = tid; i < NBKT; i += 512) lcur[i] = lbase[i];
    __syncthreads();

    // local binning (perm holds tile-local edge ids, grouped by bucket)
    for (int i = tid; i < n; i += 512) {
        int d = edge_at(ei, E + e0 + i, is64);
        int l = atomicAdd(&lcur[d >> BKT_SHIFT], 1);
        perm[l] = (unsigned short)i;
    }
    __syncthreads();

    // write out: consecutive k within a bucket-run -> consecutive positions
    for (int k = tid; k < n; k += 512) {
        int i = perm[k];
        int s = edge_at(ei, e0 + i, is64);
        int d = edge_at(ei, E + e0 + i, is64);
        int b = d >> BKT_SHIFT;
        int pos = gbase[b] + (k - lbase[b]);
        pairs[pos] = s | ((d & (BKT_NODES - 1)) << 17);
    }
}

// ---- fused CSR finalize: per bucket -> per-node counts, dinv, row_start, in-place sort
__global__ __launch_bounds__(256) void k_csr(const int* __restrict__ bkt_base,
                                             int* __restrict__ pairs,
                                             int* __restrict__ row_start,
                                             float* __restrict__ dinv) {
    __shared__ int stage[SORT_CAP];
    __shared__ int lc[BKT_NODES];
    __shared__ int rs[BKT_NODES];
    int bk = blockIdx.x, tid = threadIdx.x;
    int i0 = bkt_base[bk], i1 = bkt_base[bk + 1];
    int m = i1 - i0;
    if (tid < BKT_NODES) lc[tid] = 0;
    __syncthreads();
    for (int i = tid; i < m; i += 256) {
        int v = pairs[i0 + i];
        stage[i] = v;
        atomicAdd(&lc[v >> 17], 1);
    }
    __syncthreads();
    if (tid < BKT_NODES) rs[tid] = lc[tid];
    __syncthreads();
    for (int off = 1; off < BKT_NODES; off <<= 1) {
        int t = (tid >= off && tid < BKT_NODES) ? rs[tid - off] : 0;
        __syncthreads();
        if (tid < BKT_NODES) rs[tid] += t;
        __syncthreads();
    }
    int node = bk * BKT_NODES + tid;
    int ex = 0;
    if (tid < BKT_NODES) {
        int c = lc[tid];
        ex = rs[tid] - c;          // exclusive local prefix
        if (node < N_NODES) {
            row_start[node] = i0 + ex;
            dinv[node] = rsqrtf((float)c + 1.0f);
        }
    }
    if (bk == NBKT - 1 && tid == 0) row_start[N_NODES] = i1;
    __syncthreads();
    if (tid < BKT_NODES) lc[tid] = ex;   // reuse as cursor
    __syncthreads();
    for (int i = tid; i < m; i += 256) {
        int v = stage[i];
        int pos = atomicAdd(&lc[v >> 17], 1);
        pairs[i0 + pos] = v & 0x1FFFF;
    }
}

// ---- fused: tmpp = fp16( dinv * ( relu(x@W1+b1) @ Wc0 ) )   [skips materializing h]
__global__ __launch_bounds__(256) void k_lin1f(const float* __restrict__ x,
                                               const float* __restrict__ W1,
                                               const float* __restrict__ b1,
                                               const float* __restrict__ Wc0,
                                               const float* __restrict__ dinv,
                                               __half* __restrict__ tmpp) {
    __shared__ float sW[F_IN * HIDDEN];
    __shared__ float sb[HIDDEN];
    __shared__ float sW2[HIDDEN * HIDDEN];
    for (int i = threadIdx.x; i < F_IN * HIDDEN; i += 256) sW[i] = W1[i];
    if (threadIdx.x < HIDDEN) sb[threadIdx.x] = b1[threadIdx.x];
    if (threadIdx.x >= 32 && threadIdx.x < 32 + HIDDEN * HIDDEN)
        sW2[threadIdx.x - 32] = Wc0[threadIdx.x - 32];
    __syncthreads();
    int node = blockIdx.x * 256 + threadIdx.x;
    if (node >= N_NODES) return;

    float acc[HIDDEN];
#pragma unroll
    for (int j = 0; j < HIDDEN; ++j) acc[j] = sb[j];

    const float4* x4 = reinterpret_cast<const float4*>(x + (long long)node * F_IN);
#pragma unroll 2
    for (int k4 = 0; k4 < F_IN / 4; ++k4) {
        float4 xv = x4[k4];
        const float* w = &sW[k4 * 4 * HIDDEN];
#pragma unroll
        for (int j = 0; j < HIDDEN; ++j) {
            acc[j] += xv.x * w[0 * HIDDEN + j];
            acc[j] += xv.y * w[1 * HIDDEN + j];
            acc[j] += xv.z * w[2 * HIDDEN + j];
            acc[j] += xv.w * w[3 * HIDDEN + j];
        }
    }
#pragma unroll
    for (int j = 0; j < HIDDEN; ++j) acc[j] = fmaxf(acc[j], 0.0f);

    float out[HIDDEN];
#pragma unroll
    for (int j = 0; j < HIDDEN; ++j) out[j] = 0.0f;
#pragma unroll
    for (int k = 0; k < HIDDEN; ++k) {
        float hk = acc[k];
#pragma unroll
        for (int j = 0; j < HIDDEN; ++j) out[j] += hk * sW2[k * HIDDEN + j];
    }
    float di = dinv[node];
    __half2 packed[8];
#pragma unroll
    for (int j = 0; j < 8; ++j)
        packed[j] = __floats2half2_rn(di * out[2 * j], di * out[2 * j + 1]);
    float4* tp = reinterpret_cast<float4*>(tmpp + (long long)node * HIDDEN);
    const float4* ps = reinterpret_cast<const float4*>(packed);
    tp[0] = ps[0];
    tp[1] = ps[1];
}

// ---- tmp' = fp16( dinv[i] * (h @ W) )   [3.2 MB table -> per-XCD-L2 resident]
__global__ __launch_bounds__(256) void k_mm16(const float* __restrict__ h,
                                              const float* __restrict__ W,
                                              const float* __restrict__ dinv,
                                              __half* __restrict__ tmpp) {
    __shared__ float sW[HIDDEN * HIDDEN];
    if (threadIdx.x < HIDDEN * HIDDEN) sW[threadIdx.x] = W[threadIdx.x];
    __syncthreads();
    int node = blockIdx.x * 256 + threadIdx.x;
    if (node >= N_NODES) return;

    float hv[HIDDEN];
    const float4* hr = reinterpret_cast<const float4*>(h + (long long)node * HIDDEN);
#pragma unroll
    for (int q = 0; q < HIDDEN / 4; ++q) {
        float4 v = hr[q];
        hv[q * 4 + 0] = v.x; hv[q * 4 + 1] = v.y;
        hv[q * 4 + 2] = v.z; hv[q * 4 + 3] = v.w;
    }
    float di = dinv[node];
    float out[HIDDEN];
#pragma unroll
    for (int j = 0; j < HIDDEN; ++j) out[j] = 0.0f;
#pragma unroll
    for (int k = 0; k < HIDDEN; ++k) {
        float hk = hv[k];
#pragma unroll
        for (int j = 0; j < HIDDEN; ++j) out[j] += hk * sW[k * HIDDEN + j];
    }
    __half2 packed[8];
#pragma unroll
    for (int j = 0; j < 8; ++j)
        packed[j] = __floats2half2_rn(di * out[2 * j], di * out[2 * j + 1]);
    float4* tp = reinterpret_cast<float4*>(tmpp + (long long)node * HIDDEN);
    const float4* ps = reinterpret_cast<const float4*>(packed);
    tp[0] = ps[0];
    tp[1] = ps[1];
}

// ---- wave-per-node register pull, 4 lanes/row: lane = es*4+fq, 16 edge slots
// shrinks shuffle reduce to 4 accs x 4 rounds; fused epilogue
// h[n] = relu(dinv[n]*(sum_src tmpp[src] + tmpp[n]) + b)
__global__ __launch_bounds__(256) void k_aggr(const int* __restrict__ row_start,
                                              const int* __restrict__ srcs,
                                              const __half* __restrict__ tmpp,
                                              const float* __restrict__ dinv,
                                              const float* __restrict__ b,
                                              float* __restrict__ h) {
    int wave = (blockIdx.x * 256 + threadIdx.x) >> 6;   // node id
    if (wave >= N_NODES) return;
    int lane = threadIdx.x & 63;
    int es = lane >> 2;        // edge slot 0..15
    int fq = lane & 3;         // feature quarter (4 halves = 8 B)

    int s0 = row_start[wave], s1 = row_start[wave + 1];
    float a0 = 0.0f, a1 = 0.0f, a2 = 0.0f, a3 = 0.0f;

    for (int e = s0 + es; e < s1; e += 16) {
        int src = srcs[e];
        float2 rv = *(reinterpret_cast<const float2*>(
                          tmpp + (long long)src * HIDDEN) + fq);
        const __half2* h2 = reinterpret_cast<const __half2*>(&rv);
        float2 f0 = __half22float2(h2[0]);
        float2 f1 = __half22float2(h2[1]);
        a0 += f0.x; a1 += f0.y; a2 += f1.x; a3 += f1.y;
    }
    // reduce across the 16 edge slots (lane bits 2..5)
#pragma unroll
    for (int m = 4; m <= 32; m <<= 1) {
        a0 += __shfl_xor(a0, m);
        a1 += __shfl_xor(a1, m);
        a2 += __shfl_xor(a2, m);
        a3 += __shfl_xor(a3, m);
    }
    if (es == 0) {   // lanes 0..3: lane fq owns features fq*4 .. fq*4+3
        float2 sv = *(reinterpret_cast<const float2*>(
                          tmpp + (long long)wave * HIDDEN) + fq);
        const __half2* s2 = reinterpret_cast<const __half2*>(&sv);
        float2 f0 = __half22float2(s2[0]);
        float2 f1 = __half22float2(s2[1]);
        float di = dinv[wave];
        float4 bv = *(reinterpret_cast<const float4*>(b) + fq);
        float4 o;
        o.x = fmaxf(di * (a0 + f0.x) + bv.x, 0.0f);
        o.y = fmaxf(di * (a1 + f0.y) + bv.y, 0.0f);
        o.z = fmaxf(di * (a2 + f1.x) + bv.z, 0.0f);
        o.w = fmaxf(di * (a3 + f1.y) + bv.w, 0.0f);
        *(reinterpret_cast<float4*>(h + (long long)wave * HIDDEN) + fq) = o;
    }
}

// ---- out = log_softmax(h @ W2 + b2)
__global__ __launch_bounds__(256) void k_out(const float* __restrict__ h,
                                             const float* __restrict__ W2,
                                             const float* __restrict__ b2,
                                             float* __restrict__ out) {
    __shared__ float sW[HIDDEN * N_CLASS];
    __shared__ float sb[N_CLASS];
    for (int i = threadIdx.x; i < HIDDEN * N_CLASS; i += 256) sW[i] = W2[i];
    if (threadIdx.x < N_CLASS) sb[threadIdx.x] = b2[threadIdx.x];
    __syncthreads();
    int node = blockIdx.x * 256 + threadIdx.x;
    if (node >= N_NODES) return;

    float hv[HIDDEN];
    const float4* hr = reinterpret_cast<const float4*>(h + (long long)node * HIDDEN);
#pragma unroll
    for (int q = 0; q < HIDDEN / 4; ++q) {
        float4 v = hr[q];
        hv[q * 4 + 0] = v.x; hv[q * 4 + 1] = v.y;
        hv[q * 4 + 2] = v.z; hv[q * 4 + 3] = v.w;
    }
    float z[N_CLASS];
#pragma unroll
    for (int c = 0; c < N_CLASS; ++c) z[c] = sb[c];
#pragma unroll
    for (int k = 0; k < HIDDEN; ++k) {
        float hk = hv[k];
#pragma unroll
        for (int c = 0; c < N_CLASS; ++c) z[c] += hk * sW[k * N_CLASS + c];
    }
    float m = z[0];
#pragma unroll
    for (int c = 1; c < N_CLASS; ++c) m = fmaxf(m, z[c]);
    float ssum = 0.0f;
#pragma unroll
    for (int c = 0; c < N_CLASS; ++c) ssum += expf(z[c] - m);
    float l = m + logf(ssum);
    float* orow = out + (long long)node * N_CLASS;
#pragma unroll
    for (int c = 0; c < N_CLASS; ++c) orow[c] = z[c] - l;
}

static inline char* align256(char* p) {
    return (char*)(((size_t)p + 255) & ~(size_t)255);
}

extern "C" void kernel_launch(void* const* d_in, const int* in_sizes, int n_in,
                              void* d_out, int out_size, void* d_ws, size_t ws_size,
                              hipStream_t stream) {
    const float* x   = (const float*)d_in[0];
    const int*   ei  = (const int*)d_in[1];
    const float* W1  = (const float*)d_in[2];
    const float* b1  = (const float*)d_in[3];
    const float* Wc0 = (const float*)d_in[4];
    const float* bc0 = (const float*)d_in[5];
    const float* Wc1 = (const float*)d_in[6];
    const float* bc1 = (const float*)d_in[7];
    const float* W2  = (const float*)d_in[8];
    const float* b2  = (const float*)d_in[9];
    float* out = (float*)d_out;

    long long E = (long long)in_sizes[1] / 2;

    char* p = (char*)d_ws;
    float* dinv    = (float*)p;          p = align256(p + sizeof(float) * N_NODES);
    int* row_start = (int*)p;            p = align256(p + sizeof(int) * (N_NODES + 1));
    int* bcnt      = (int*)p;            p = align256(p + sizeof(int) * NBKT);
    int* bkt_base  = (int*)p;            p = align256(p + sizeof(int) * (NBKT + 1));
    int* gcur      = (int*)p;            p = align256(p + sizeof(int) * NBKT);
    int* pairs     = (int*)p;            p = align256(p + sizeof(int) * E);
    float* h       = (float*)p;          p = align256(p + sizeof(float) * (size_t)N_NODES * HIDDEN);
    __half* tmpp   = (__half*)p;         p = align256(p + sizeof(__half) * (size_t)N_NODES * HIDDEN);

    const int nblk_node   = (N_NODES + 255) / 256;
    const int nblk_bucket = (int)((E + TILE - 1) / TILE);
    const int nblk_aggr   = (int)(((long long)N_NODES * 64 + 255) / 256);

    hipMemsetAsync(bcnt, 0, sizeof(int) * NBKT, stream);

    k_bcnt<<<nblk_bucket, 512, 0, stream>>>(ei, E, bcnt);
    k_bktscan<<<1, 1024, 0, stream>>>(bcnt, gcur, bkt_base);
    k_bucket<<<nblk_bucket, 512, 0, stream>>>(ei, E, gcur, pairs);
    k_csr<<<NBKT, 256, 0, stream>>>(bkt_base, pairs, row_start, dinv);

    // conv 1 (lin1 fused into the dense transform)
    k_lin1f<<<nblk_node, 256, 0, stream>>>(x, W1, b1, Wc0, dinv, tmpp);
    k_aggr<<<nblk_aggr, 256, 0, stream>>>(row_start, pairs, tmpp, dinv, bc0, h);

    // conv 2
    k_mm16<<<nblk_node, 256, 0, stream>>>(h, Wc1, dinv, tmpp);
    k_aggr<<<nblk_aggr, 256, 0, stream>>>(row_start, pairs, tmpp, dinv, bc1, h);

    k_out<<<nblk_node, 256, 0, stream>>>(h, W2, b2, out);
}